// Round 3
// baseline (367.453 us; speedup 1.0000x reference)
//
#include <hip/hip_runtime.h>
#include <hip/hip_bf16.h>

typedef __hip_bfloat16 bf16;
typedef unsigned short ushort_t;
typedef __attribute__((ext_vector_type(8))) short short8;
typedef __attribute__((ext_vector_type(4))) float float4v;

#define BATCH 4
#define HH 512
#define WW 512

// transposed-weight stash offsets (bf16 elems, at head of d_out; patches_k overwrites LAST)
#define WO_L0 0        // conv0 tap-packed [tl(4)][g(3)][o(32)][c(8)] = 3072
#define WO_L1 3072     // [ch][tap][32][32] = 9216
#define WO_L2 12288    // [ch][tap][64][32] = 18432
#define WO_L3 30720    // [ch2][tap][64][32] = 36864
#define WO_L4P 67584   // phase [ph4][ch2][tap][64][32] = 147456
#define WO_L5 215040   // [ch2][tap][32][32] = 18432
#define WO_L6P 233472  // phase [ph4][ch1][tap][32][32] = 36864
#define WO_L7 270336   // [ch][tap][16][32] = 4608
#define WO_L4U 274944  // unfused L4 [ch2][tap][64][32] = 36864 (for conv_edge)
#define WO_L6U 311808  // unfused L6 [ch1][tap][32][32] = 9216  (for conv_edge)

__device__ __forceinline__ ushort_t f2bfu(float f) {
  __hip_bfloat16 h = __float2bfloat16(f);
  union { __hip_bfloat16 h; ushort_t u; } c;
  c.h = h;
  return c.u;
}
__device__ __forceinline__ float bfu2f(ushort_t u) {
  return __uint_as_float(((unsigned)u) << 16);
}

// async global->LDS DMA, 16 B per lane; LDS dest = wave-uniform base + lane*16
__device__ __forceinline__ void dma16(void* lds, const void* g) {
  __builtin_amdgcn_global_load_lds(
      (const __attribute__((address_space(1))) unsigned int*)g,
      (__attribute__((address_space(3))) unsigned int*)lds, 16, 0, 0);
}

// bilinear x2 (half-pixel) row kernel: weight of src[i-1+u] in up[2i+dy-1+r].
__device__ __forceinline__ float upw(int k, int u) {
  int lo = k >> 1;
  float a = (k & 1) ? 0.25f : 0.75f;
  float b = (k & 1) ? 0.75f : 0.25f;
  return (u == lo) ? a : (u == lo + 1) ? b : 0.0f;
}

// ---------------------------------------------------------------------------
// Weight prep. Jobs:
//  0        : conv0 tap-packed  [tl][g][o][c8]  (k = tl*8+c, tap = g*4+tl)
//  4, 6     : phase-folded upsample+conv weights [ph][ch][tap][OP][32]
//  1,2,3,5,7: standard per-chunk [ch][tap][OP][32]
//  8, 9     : UNFUSED L4/L6 per-chunk [ch][tap][OP][32] (for conv_edge)
// ---------------------------------------------------------------------------
struct WP { const float* w[8]; };

__global__ __launch_bounds__(256) void prep_w(WP wp, bf16* __restrict__ dst) {
  const int job = blockIdx.y;
  const int e = blockIdx.x * 256 + threadIdx.x;
  if (job == 0) {
    if (e >= 3072) return;
    int c = e & 7;
    int o = (e >> 3) & 31;
    int g = (e >> 8) % 3;
    int tl = (e >> 8) / 3;
    int tap = g * 4 + tl;
    float v = 0.0f;
    if (tap < 9 && c < 3) v = wp.w[0][(o * 3 + c) * 9 + tap];
    dst[WO_L0 + e] = __float2bfloat16(v);
    return;
  }
  if (job == 4 || job == 6) {
    const int O = (job == 4) ? 64 : 32;
    const int I = O;
    const int NCH = I >> 5;
    const int n = 4 * NCH * 9 * O * 32;
    if (e >= n) return;
    int ic = e & 31;
    int o = (e >> 5) % O;
    int tap = (e / (32 * O)) % 9;
    int ch = (e / (9 * 32 * O)) % NCH;
    int ph = e / (NCH * 9 * 32 * O);
    int i = ch * 32 + ic;
    int u = tap / 3, v2 = tap - u * 3;
    int dy = ph >> 1, dx = ph & 1;
    const float* w = wp.w[job];
    float acc = 0.0f;
#pragma unroll
    for (int r = 0; r < 3; ++r) {
      float ry = upw(r + dy, u);
#pragma unroll
      for (int s = 0; s < 3; ++s)
        acc += w[(o * I + i) * 9 + r * 3 + s] * ry * upw(s + dx, v2);
    }
    dst[((job == 4) ? WO_L4P : WO_L6P) + e] = __float2bfloat16(acc);
    return;
  }
  int O, I, OP, off;
  const float* w;
  if (job == 1)      { O = 32; I = 32; OP = 32; off = WO_L1; w = wp.w[1]; }
  else if (job == 2) { O = 64; I = 32; OP = 64; off = WO_L2; w = wp.w[2]; }
  else if (job == 3) { O = 64; I = 64; OP = 64; off = WO_L3; w = wp.w[3]; }
  else if (job == 5) { O = 32; I = 64; OP = 32; off = WO_L5; w = wp.w[5]; }
  else if (job == 7) { O = 2;  I = 32; OP = 16; off = WO_L7; w = wp.w[7]; }
  else if (job == 8) { O = 64; I = 64; OP = 64; off = WO_L4U; w = wp.w[4]; }
  else               { O = 32; I = 32; OP = 32; off = WO_L6U; w = wp.w[6]; }
  const int NCH = I >> 5;
  const int n = NCH * 9 * OP * 32;
  if (e >= n) return;
  int ic = e & 31;
  int o = (e >> 5) % OP;
  int tap = (e / (32 * OP)) % 9;
  int ch = e / (9 * 32 * OP);
  int i = ch * 32 + ic;
  float v = 0.0f;
  if (o < O) v = w[(o * I + i) * 9 + tap];
  dst[off + e] = __float2bfloat16(v);
}

// ---------------------------------------------------------------------------
// pack_x: NCHW f32 (3ch) -> NHWC-8 bf16 (ch 3..7 zero)
// ---------------------------------------------------------------------------
__global__ __launch_bounds__(256) void pack_x(const float* __restrict__ x,
                                              bf16* __restrict__ xp) {
  int i = blockIdx.x * 256 + threadIdx.x;
  if (i >= BATCH * HH * WW) return;
  int b = i / (HH * WW);
  int px = i - b * (HH * WW);
  union { uint4 v; ushort_t s[8]; } o;
  o.v = make_uint4(0, 0, 0, 0);
  const float* p = x + (long)b * 3 * HH * WW + px;
  o.s[0] = f2bfu(p[0]);
  o.s[1] = f2bfu(p[HH * WW]);
  o.s[2] = f2bfu(p[2 * HH * WW]);
  *(uint4*)&xp[(long)i * 8] = o.v;
}

// ---------------------------------------------------------------------------
// conv0: tap-packed K (4 taps x 8ch = K32). 8 waves, 32(t) x 16(w) tile.
// ---------------------------------------------------------------------------
__global__ __launch_bounds__(512) void conv0_k(
    const bf16* __restrict__ xp, const bf16* __restrict__ wt,
    const float* __restrict__ bias, bf16* __restrict__ out) {
  __shared__ alignas(16) bf16 in_lds[612 * 8];  // 34x18 halo x 8ch
  __shared__ alignas(16) bf16 w_lds[3072];
  const int tid = threadIdx.x;
  const int lane = tid & 63;
  const int wid = tid >> 6;  // 0..7
  const int lm = lane & 15;
  const int quad = lane >> 4;
  const int x0 = blockIdx.x * 16, y0 = blockIdx.y * 32;
  const int b = blockIdx.z;

#pragma unroll
  for (int k = 0; k < 2; ++k) {
    int u = tid + k * 512;
    if (u < 612) {
      int hy = u / 18, hx = u - hy * 18;
      int gy = y0 - 1 + hy, gx = x0 - 1 + hx;
      uint4 v = make_uint4(0, 0, 0, 0);
      if (gy >= 0 && gy < HH && gx >= 0 && gx < WW)
        v = *(const uint4*)(xp + (((long)b * HH + gy) * WW + gx) * 8);
      *(uint4*)&in_lds[u * 8] = v;
    }
  }
  if (tid < 384) *(uint4*)&w_lds[tid * 8] = *(const uint4*)(wt + tid * 8);
  __syncthreads();

  float4v acc[2][4];
#pragma unroll
  for (int mt = 0; mt < 2; ++mt) {
    float4v bv = *(const float4v*)(bias + mt * 16 + quad * 4);
#pragma unroll
    for (int nt = 0; nt < 4; ++nt) acc[mt][nt] = bv;
  }

#pragma unroll
  for (int g = 0; g < 3; ++g) {
    int tap = g * 4 + quad;
    if (tap > 8) tap = 8;  // clamped taps have zero A-weights
    int r = (tap * 11) >> 5;
    int s = tap - r * 3;
    short8 afrag[2], bfrag[4];
#pragma unroll
    for (int mt = 0; mt < 2; ++mt)
      afrag[mt] = *(const short8*)&w_lds[quad * 768 + (g * 32 + mt * 16 + lm) * 8];
#pragma unroll
    for (int nt = 0; nt < 4; ++nt) {
      int py = 4 * wid + nt;
      bfrag[nt] = *(const short8*)&in_lds[((py + r) * 18 + lm + s) * 8];
    }
#pragma unroll
    for (int mt = 0; mt < 2; ++mt)
#pragma unroll
      for (int nt = 0; nt < 4; ++nt)
        acc[mt][nt] = __builtin_amdgcn_mfma_f32_16x16x32_bf16(
            afrag[mt], bfrag[nt], acc[mt][nt], 0, 0, 0);
  }

#pragma unroll
  for (int mt = 0; mt < 2; ++mt)
#pragma unroll
    for (int nt = 0; nt < 4; ++nt) {
      int gy = y0 + 4 * wid + nt, gx = x0 + lm;
      union { uint2 v; ushort_t s2[4]; } pk;
#pragma unroll
      for (int r2 = 0; r2 < 4; ++r2) pk.s2[r2] = f2bfu(fmaxf(acc[mt][nt][r2], 0.0f));
      *(uint2*)&out[(((long)b * HH + gy) * WW + gx) * 32 + mt * 16 + quad * 4] = pk.v;
    }
}

// ---------------------------------------------------------------------------
// Implicit-GEMM 3x3 conv (pad 1), NHWC bf16. 8 waves, 32(t) x 16(w) tile.
// OUT_MODE: 0 = NHWC bf16 (+relu); 2 = flow NCHW f32 (tanh) + fused deformed;
//           3 = NHWC bf16, fused relu + 2x2 maxpool.
// ---------------------------------------------------------------------------
template <int CIN, int COUT, int COUTR, int OUT_MODE>
__global__ __launch_bounds__(512) void conv_mfma(
    const bf16* __restrict__ in, const bf16* __restrict__ wt,
    const float* __restrict__ bias, void* __restrict__ out_, int H, int W,
    const float* __restrict__ temp, float* __restrict__ def) {
  constexpr int MT = COUT / 16;
  constexpr int CK = 32;
  __shared__ alignas(16) bf16 in_lds[612 * CK];  // 34x18 halo x 32ch
  __shared__ alignas(16) bf16 w_lds[9 * COUT * CK];
  const int tid = threadIdx.x;
  const int lane = tid & 63;
  const int wid = tid >> 6;  // 0..7
  const int lm = lane & 15;
  const int quad = lane >> 4;
  const int x0 = blockIdx.x * 16;
  const int y0 = blockIdx.y * 32;
  const int b = blockIdx.z;

  float4v acc[MT][4];
#pragma unroll
  for (int mt = 0; mt < MT; ++mt) {
    float4v bv;
    if constexpr (COUTR == COUT) {
      bv = *(const float4v*)(bias + mt * 16 + quad * 4);
    } else {
#pragma unroll
      for (int r = 0; r < 4; ++r) {
        int co = mt * 16 + quad * 4 + r;
        bv[r] = (co < COUTR) ? bias[co] : 0.0f;
      }
    }
#pragma unroll
    for (int nt = 0; nt < 4; ++nt) acc[mt][nt] = bv;
  }

  const bool interior =
      (x0 >= 1) && (x0 + 16 <= W - 1) && (y0 >= 1) && (y0 + 32 <= H - 1);
  for (int c0 = 0; c0 < CIN; c0 += CK) {
    if (interior) {
      for (int r = wid; r < 34; r += 8) {
        int gy = y0 - 1 + r;
        const bf16* gsrc = in + (((long)b * H + gy) * W + x0) * CIN + c0 +
                           (lane >> 2) * CIN + (lane & 3) * 8;
        dma16(&in_lds[(r * 18 + 1) * CK], gsrc);
      }
      if (tid < 272) {
        int r = tid >> 3;
        int side = (tid >> 2) & 1;
        int seg = tid & 3;
        int gx = side ? (x0 + 16) : (x0 - 1);
        int gy = y0 - 1 + r;
        uint4 v = *(const uint4*)(in + (((long)b * H + gy) * W + gx) * CIN +
                                  c0 + seg * 8);
        *(uint4*)&in_lds[(r * 18 + (side ? 17 : 0)) * CK + seg * 8] = v;
      }
    } else {
      for (int u = tid; u < 612 * 4; u += 512) {
        int px = u >> 2;
        int seg = u & 3;
        int hy = px / 18, hx = px - hy * 18;
        int gy = y0 - 1 + hy, gx = x0 - 1 + hx;
        uint4 v = make_uint4(0, 0, 0, 0);
        if (gy >= 0 && gy < H && gx >= 0 && gx < W)
          v = *(const uint4*)(in + (((long)b * H + gy) * W + gx) * CIN + c0 +
                              seg * 8);
        *(uint4*)&in_lds[px * CK + seg * 8] = v;
      }
    }
    {
      const char* wsrc = (const char*)(wt + (size_t)(c0 >> 5) * 9 * COUT * CK);
      constexpr int WCH = 9 * COUT * CK * 2 / 1024;
      for (int j = wid; j < WCH; j += 8)
        dma16((char*)w_lds + j * 1024, wsrc + j * 1024 + lane * 16);
    }
    __syncthreads();

#pragma unroll
    for (int tap = 0; tap < 9; ++tap) {
      const int r = tap / 3, s = tap - r * 3;
      short8 afrag[MT], bfrag[4];
#pragma unroll
      for (int mt = 0; mt < MT; ++mt)
        afrag[mt] =
            *(const short8*)&w_lds[(tap * COUT + mt * 16 + lm) * CK + quad * 8];
#pragma unroll
      for (int nt = 0; nt < 4; ++nt) {
        int py = 4 * wid + nt;
        bfrag[nt] =
            *(const short8*)&in_lds[((py + r) * 18 + lm + s) * CK + quad * 8];
      }
#pragma unroll
      for (int mt = 0; mt < MT; ++mt)
#pragma unroll
        for (int nt = 0; nt < 4; ++nt)
          acc[mt][nt] = __builtin_amdgcn_mfma_f32_16x16x32_bf16(
              afrag[mt], bfrag[nt], acc[mt][nt], 0, 0, 0);
    }
    __syncthreads();
  }

  if constexpr (OUT_MODE == 3) {
    bf16* out = (bf16*)out_;
    const int Ho = H >> 1, Wo = W >> 1;
#pragma unroll
    for (int mt = 0; mt < MT; ++mt) {
#pragma unroll
      for (int g = 0; g < 2; ++g) {
        float4v m;
#pragma unroll
        for (int r = 0; r < 4; ++r)
          m[r] = fmaxf(fmaxf(acc[mt][2 * g][r], acc[mt][2 * g + 1][r]), 0.0f);
#pragma unroll
        for (int r = 0; r < 4; ++r) m[r] = fmaxf(m[r], __shfl_xor(m[r], 1, 64));
        if ((lm & 1) == 0) {
          int pyo = (y0 >> 1) + 2 * wid + g;
          int pxo = (x0 >> 1) + (lm >> 1);
          union { uint2 v; ushort_t s[4]; } pk;
#pragma unroll
          for (int r = 0; r < 4; ++r) pk.s[r] = f2bfu(m[r]);
          *(uint2*)&out[(((long)b * Ho + pyo) * Wo + pxo) * COUT + mt * 16 +
                        quad * 4] = pk.v;
        }
      }
    }
  } else {
#pragma unroll
    for (int mt = 0; mt < MT; ++mt) {
#pragma unroll
      for (int nt = 0; nt < 4; ++nt) {
        int gy = y0 + 4 * wid + nt;
        int gx = x0 + lm;
        float4v v = acc[mt][nt];
        if constexpr (OUT_MODE == 0) {
          bf16* out = (bf16*)out_;
          union { uint2 v; ushort_t s[4]; } pk;
#pragma unroll
          for (int r = 0; r < 4; ++r) pk.s[r] = f2bfu(fmaxf(v[r], 0.0f));
          *(uint2*)&out[(((long)b * H + gy) * W + gx) * COUT + mt * 16 +
                        quad * 4] = pk.v;
        } else {
          float* out = (float*)out_;
          if (quad == 0) {
            float fx = tanhf(v[0]);
            float fy = tanhf(v[1]);
            out[(((long)b * 2 + 0) * H + gy) * (long)W + gx] = fx;
            out[(((long)b * 2 + 1) * H + gy) * (long)W + gx] = fy;
            float T = temp[0];
            float2 d;
            d.x = -1.0f + gx * (2.0f / 511.0f) + fx * T;
            d.y = -1.0f + gy * (2.0f / 511.0f) + fy * T;
            *(float2*)&def[(((long)b * HH + gy) * WW + gx) * 2] = d;
          }
        }
      }
    }
  }
}

// ---------------------------------------------------------------------------
// conv_up: fused (x2 bilinear upsample -> 3x3 conv -> relu) as 4 phase-convs
// on the HALF-res grid with prep-folded phase weights. 8 waves, 32x16 src
// tile = 64x32 output. Exact except the 1-px output ring -> conv_edge.
// ---------------------------------------------------------------------------
template <int CIN, int COUT>
__global__ __launch_bounds__(512) void conv_up(
    const bf16* __restrict__ in, const bf16* __restrict__ wt,
    const float* __restrict__ bias, bf16* __restrict__ out, int Ho, int Wo) {
  constexpr int MT = COUT / 16;
  constexpr int CK = 32;
  __shared__ alignas(16) bf16 in_lds[612 * CK];
  __shared__ alignas(16) bf16 w_lds[9 * COUT * CK];
  const int tid = threadIdx.x;
  const int lane = tid & 63;
  const int wid = tid >> 6;
  const int lm = lane & 15;
  const int quad = lane >> 4;
  const int Hs = Ho >> 1, Ws = Wo >> 1;
  const int bx = blockIdx.x, by = blockIdx.y;
  const int xs0 = bx * 16, ys0 = by * 32;
  const int b = blockIdx.z;
  const bool interior = (bx >= 1) && (bx < (Ws >> 4) - 1) && (by >= 1) &&
                        (by < (Hs >> 5) - 1);

  for (int ph = 0; ph < 4; ++ph) {
    float4v acc[MT][4];
#pragma unroll
    for (int mt = 0; mt < MT; ++mt) {
      float4v bv = *(const float4v*)(bias + mt * 16 + quad * 4);
#pragma unroll
      for (int nt = 0; nt < 4; ++nt) acc[mt][nt] = bv;
    }
    for (int c0 = 0; c0 < CIN; c0 += CK) {
      if (ph == 0 || CIN > CK) {
        if (interior) {
          for (int r = wid; r < 34; r += 8) {
            int gy = ys0 - 1 + r;
            const bf16* gsrc = in + (((long)b * Hs + gy) * Ws + xs0) * CIN +
                               c0 + (lane >> 2) * CIN + (lane & 3) * 8;
            dma16(&in_lds[(r * 18 + 1) * CK], gsrc);
          }
          if (tid < 272) {
            int r = tid >> 3;
            int side = (tid >> 2) & 1;
            int seg = tid & 3;
            int gx = side ? (xs0 + 16) : (xs0 - 1);
            int gy = ys0 - 1 + r;
            uint4 v = *(const uint4*)(in + (((long)b * Hs + gy) * Ws + gx) * CIN +
                                      c0 + seg * 8);
            *(uint4*)&in_lds[(r * 18 + (side ? 17 : 0)) * CK + seg * 8] = v;
          }
        } else {
          for (int u = tid; u < 612 * 4; u += 512) {
            int px = u >> 2;
            int seg = u & 3;
            int hy = px / 18, hx = px - hy * 18;
            int sy = min(max(ys0 - 1 + hy, 0), Hs - 1);
            int sx = min(max(xs0 - 1 + hx, 0), Ws - 1);
            uint4 v = *(const uint4*)(in + (((long)b * Hs + sy) * Ws + sx) * CIN +
                                      c0 + seg * 8);
            *(uint4*)&in_lds[px * CK + seg * 8] = v;
          }
        }
      }
      {
        const char* wsrc = (const char*)(wt + (size_t)(ph * (CIN / CK) + (c0 >> 5)) *
                                                  9 * COUT * CK);
        constexpr int WCH = 9 * COUT * CK * 2 / 1024;
        for (int j = wid; j < WCH; j += 8)
          dma16((char*)w_lds + j * 1024, wsrc + j * 1024 + lane * 16);
      }
      __syncthreads();
#pragma unroll
      for (int tap = 0; tap < 9; ++tap) {
        const int r = tap / 3, s = tap - r * 3;
        short8 afrag[MT], bfrag[4];
#pragma unroll
        for (int mt = 0; mt < MT; ++mt)
          afrag[mt] =
              *(const short8*)&w_lds[(tap * COUT + mt * 16 + lm) * CK + quad * 8];
#pragma unroll
        for (int nt = 0; nt < 4; ++nt) {
          int py = 4 * wid + nt;
          bfrag[nt] =
              *(const short8*)&in_lds[((py + r) * 18 + lm + s) * CK + quad * 8];
        }
#pragma unroll
        for (int mt = 0; mt < MT; ++mt)
#pragma unroll
          for (int nt = 0; nt < 4; ++nt)
            acc[mt][nt] = __builtin_amdgcn_mfma_f32_16x16x32_bf16(
                afrag[mt], bfrag[nt], acc[mt][nt], 0, 0, 0);
      }
      __syncthreads();
    }
    const int dy = ph >> 1, dx = ph & 1;
#pragma unroll
    for (int mt = 0; mt < MT; ++mt)
#pragma unroll
      for (int nt = 0; nt < 4; ++nt) {
        int gy = 2 * (ys0 + 4 * wid + nt) + dy;
        int gx = 2 * (xs0 + lm) + dx;
        union { uint2 v; ushort_t s2[4]; } pk;
#pragma unroll
        for (int r2 = 0; r2 < 4; ++r2)
          pk.s2[r2] = f2bfu(fmaxf(acc[mt][nt][r2], 0.0f));
        *(uint2*)&out[(((long)b * Ho + gy) * Wo + gx) * COUT + mt * 16 +
                      quad * 4] = pk.v;
      }
  }
}

// ---------------------------------------------------------------------------
// conv_edge: exact fused upsample->conv->relu (on-the-fly bilinear staging,
// zero outside full-res image, clamp at src edges) for PERIMETER 16x16 output
// tiles only. Overwrites conv_up's ring.
// ---------------------------------------------------------------------------
template <int CIN, int COUT>
__global__ __launch_bounds__(256) void conv_edge(
    const bf16* __restrict__ in, const bf16* __restrict__ wt,
    const float* __restrict__ bias, bf16* __restrict__ out, int H, int W) {
  constexpr int MT = COUT / 16;
  constexpr int CK = 32;
  __shared__ alignas(16) bf16 in_lds[324 * CK];
  __shared__ alignas(16) bf16 w_lds[9 * COUT * CK];
  const int tid = threadIdx.x;
  const int lane = tid & 63;
  const int wid = tid >> 6;
  const int lm = lane & 15;
  const int quad = lane >> 4;
  const int G = W >> 4;
  int t = blockIdx.x;
  int tx, ty;
  if (t < G) { ty = 0; tx = t; }
  else if (t < 2 * G) { ty = G - 1; tx = t - G; }
  else { int u = t - 2 * G; ty = 1 + (u >> 1); tx = (u & 1) ? (G - 1) : 0; }
  const int x0 = tx * 16, y0 = ty * 16;
  const int b = blockIdx.z;
  const int Hs = H >> 1, Ws = W >> 1;

  float4v acc[MT][4];
#pragma unroll
  for (int mt = 0; mt < MT; ++mt) {
    float4v bv = *(const float4v*)(bias + mt * 16 + quad * 4);
#pragma unroll
    for (int nt = 0; nt < 4; ++nt) acc[mt][nt] = bv;
  }

  for (int c0 = 0; c0 < CIN; c0 += CK) {
    for (int u = tid; u < 324 * 4; u += 256) {
      int px = u >> 2;
      int seg = u & 3;
      int hy = px / 18, hx = px - hy * 18;
      int gy = y0 - 1 + hy, gx = x0 - 1 + hx;
      uint4 o = make_uint4(0, 0, 0, 0);
      if (gy >= 0 && gy < H && gx >= 0 && gx < W) {
        int ys = (gy >> 1) - ((gy & 1) ? 0 : 1);
        int xs = (gx >> 1) - ((gx & 1) ? 0 : 1);
        float wy = (gy & 1) ? 0.25f : 0.75f;
        float wx = (gx & 1) ? 0.25f : 0.75f;
        int y0c = max(ys, 0), y1c = min(ys + 1, Hs - 1);
        int x0c = max(xs, 0), x1c = min(xs + 1, Ws - 1);
        const bf16* p = in + ((long)b * Hs * Ws) * CIN + c0 + seg * 8;
        union { uint4 v; ushort_t s[8]; } a00, a01, a10, a11, r;
        a00.v = *(const uint4*)(p + ((long)y0c * Ws + x0c) * CIN);
        a01.v = *(const uint4*)(p + ((long)y0c * Ws + x1c) * CIN);
        a10.v = *(const uint4*)(p + ((long)y1c * Ws + x0c) * CIN);
        a11.v = *(const uint4*)(p + ((long)y1c * Ws + x1c) * CIN);
#pragma unroll
        for (int j = 0; j < 8; ++j) {
          float f = (1.0f - wy) * ((1.0f - wx) * bfu2f(a00.s[j]) +
                                   wx * bfu2f(a01.s[j])) +
                    wy * ((1.0f - wx) * bfu2f(a10.s[j]) +
                          wx * bfu2f(a11.s[j]));
          r.s[j] = f2bfu(f);
        }
        o = r.v;
      }
      *(uint4*)&in_lds[px * CK + seg * 8] = o;
    }
    {
      const char* wsrc = (const char*)(wt + (size_t)(c0 >> 5) * 9 * COUT * CK);
      constexpr int WCH = 9 * COUT * CK * 2 / 1024;
      for (int j = wid; j < WCH; j += 4)
        dma16((char*)w_lds + j * 1024, wsrc + j * 1024 + lane * 16);
    }
    __syncthreads();
#pragma unroll
    for (int tap = 0; tap < 9; ++tap) {
      const int r = tap / 3, s = tap - r * 3;
      short8 afrag[MT], bfrag[4];
#pragma unroll
      for (int mt = 0; mt < MT; ++mt)
        afrag[mt] =
            *(const short8*)&w_lds[(tap * COUT + mt * 16 + lm) * CK + quad * 8];
#pragma unroll
      for (int nt = 0; nt < 4; ++nt) {
        int py = 4 * wid + nt;
        bfrag[nt] =
            *(const short8*)&in_lds[((py + r) * 18 + lm + s) * CK + quad * 8];
      }
#pragma unroll
      for (int mt = 0; mt < MT; ++mt)
#pragma unroll
        for (int nt = 0; nt < 4; ++nt)
          acc[mt][nt] = __builtin_amdgcn_mfma_f32_16x16x32_bf16(
              afrag[mt], bfrag[nt], acc[mt][nt], 0, 0, 0);
    }
    __syncthreads();
  }

#pragma unroll
  for (int mt = 0; mt < MT; ++mt)
#pragma unroll
    for (int nt = 0; nt < 4; ++nt) {
      int gy = y0 + 4 * wid + nt;
      int gx = x0 + lm;
      union { uint2 v; ushort_t s[4]; } pk;
#pragma unroll
      for (int r = 0; r < 4; ++r) pk.s[r] = f2bfu(fmaxf(acc[mt][nt][r], 0.0f));
      *(uint2*)&out[(((long)b * H + gy) * W + gx) * COUT + mt * 16 +
                    quad * 4] = pk.v;
    }
}

// ---------------------------------------------------------------------------
// patches: grid_sample bilinear, zeros padding -> out [B,256,3,64,64]
// ---------------------------------------------------------------------------
__global__ __launch_bounds__(256) void patches_k(const float* __restrict__ x,
                                                 const float* __restrict__ def,
                                                 float* __restrict__ out) {
  int i = blockIdx.x * 256 + threadIdx.x;
  int pj = i & 63;
  int t = i >> 6;
  int pi = t & 63;
  t >>= 6;
  int n = t & 255;
  int b = t >> 8;
  if (b >= BATCH) return;
  int hi = n >> 4, wi = n & 15;
  const float* dptr = def + (((long)b * HH + hi * 32) * WW + wi * 32) * 2;
  float cx = dptr[0], cy = dptr[1];
  float pgx = cx + (-1.0f + pj * (2.0f / 63.0f)) * 0.125f;
  float pgy = cy + (-1.0f + pi * (2.0f / 63.0f)) * 0.125f;
  float ix = ((pgx + 1.0f) * 512.0f - 1.0f) * 0.5f;
  float iy = ((pgy + 1.0f) * 512.0f - 1.0f) * 0.5f;
  float fx0 = floorf(ix), fy0 = floorf(iy);
  float wx1 = ix - fx0, wy1 = iy - fy0;
  int x0 = (int)fx0, y0 = (int)fy0;
  int x1 = x0 + 1, y1 = y0 + 1;
  bool vx0 = (x0 >= 0) && (x0 <= 511), vx1 = (x1 >= 0) && (x1 <= 511);
  bool vy0 = (y0 >= 0) && (y0 <= 511), vy1 = (y1 >= 0) && (y1 <= 511);
  int cx0 = min(max(x0, 0), 511), cx1 = min(max(x1, 0), 511);
  int cy0 = min(max(y0, 0), 511), cy1 = min(max(y1, 0), 511);
  float w00 = (1.0f - wx1) * (1.0f - wy1) * ((vx0 && vy0) ? 1.0f : 0.0f);
  float w01 = wx1 * (1.0f - wy1) * ((vx1 && vy0) ? 1.0f : 0.0f);
  float w10 = (1.0f - wx1) * wy1 * ((vx0 && vy1) ? 1.0f : 0.0f);
  float w11 = wx1 * wy1 * ((vx1 && vy1) ? 1.0f : 0.0f);
#pragma unroll
  for (int c = 0; c < 3; ++c) {
    const float* img = x + ((long)b * 3 + c) * (HH * WW);
    float v = img[cy0 * WW + cx0] * w00 + img[cy0 * WW + cx1] * w01 +
              img[cy1 * WW + cx0] * w10 + img[cy1 * WW + cx1] * w11;
    out[(((long)b * 256 + n) * 3 + c) * 4096 + pi * 64 + pj] = v;
  }
}

// ---------------------------------------------------------------------------

extern "C" void kernel_launch(void* const* d_in, const int* in_sizes, int n_in,
                              void* d_out, int out_size, void* d_ws,
                              size_t ws_size, hipStream_t stream) {
  const float* x = (const float*)d_in[0];
  WP wp;
  const float* bs[8];
  for (int i = 0; i < 8; ++i) {
    wp.w[i] = (const float*)d_in[1 + 2 * i];
    bs[i] = (const float*)d_in[2 + 2 * i];
  }
  const float* temp = (const float*)d_in[17];

  float* out = (float*)d_out;
  float* flow = out + 12582912;  // [B,2,512,512] f32
  float* def = out + 14680064;   // [B,512,512,2] f32
  bf16* wT = (bf16*)d_out;       // weight stash; patches_k overwrites LAST

  const size_t bufElems = (size_t)BATCH * 512 * 512 * 32;
  bf16* A = (bf16*)d_ws;
  bf16* Bf = A + bufElems;
  bf16* xp = Bf + bufElems;

  prep_w<<<dim3(576, 10), 256, 0, stream>>>(wp, wT);
  pack_x<<<(BATCH * HH * WW) / 256, 256, 0, stream>>>(x, xp);

  // conv0 (tap-packed): xp -> A [512,512,32]
  conv0_k<<<dim3(32, 16, BATCH), 512, 0, stream>>>(xp, wT + WO_L0, bs[0], A);
  // conv1 + relu + pool: A -> Bf [256,256,32]
  conv_mfma<32, 32, 32, 3><<<dim3(32, 16, BATCH), 512, 0, stream>>>(
      A, wT + WO_L1, bs[1], Bf, 512, 512, nullptr, nullptr);
  // conv2: Bf -> A [256,256,64]
  conv_mfma<32, 64, 64, 0><<<dim3(16, 8, BATCH), 512, 0, stream>>>(
      Bf, wT + WO_L2, bs[2], A, 256, 256, nullptr, nullptr);
  // conv3 + relu + pool: A -> Bf [128,128,64]
  conv_mfma<64, 64, 64, 3><<<dim3(16, 8, BATCH), 512, 0, stream>>>(
      A, wT + WO_L3, bs[3], Bf, 256, 256, nullptr, nullptr);
  // conv4 (phase-decomposed up1): Bf(128² src) -> A [256,256,64]
  conv_up<64, 64><<<dim3(8, 4, BATCH), 512, 0, stream>>>(Bf, wT + WO_L4P, bs[4], A, 256, 256);
  // exact perimeter tiles (60 = 4*16-4)
  conv_edge<64, 64><<<dim3(60, 1, BATCH), 256, 0, stream>>>(Bf, wT + WO_L4U, bs[4], A, 256, 256);
  // conv5: A -> Bf [256,256,32]
  conv_mfma<64, 32, 32, 0><<<dim3(16, 8, BATCH), 512, 0, stream>>>(
      A, wT + WO_L5, bs[5], Bf, 256, 256, nullptr, nullptr);
  // conv6 (phase-decomposed up2): Bf(256² src) -> A [512,512,32]
  conv_up<32, 32><<<dim3(16, 8, BATCH), 512, 0, stream>>>(Bf, wT + WO_L6P, bs[6], A, 512, 512);
  // exact perimeter tiles (124 = 4*32-4)
  conv_edge<32, 32><<<dim3(124, 1, BATCH), 256, 0, stream>>>(Bf, wT + WO_L6U, bs[6], A, 512, 512);
  // conv7 + tanh + fused deformed: A -> flow + def
  conv_mfma<32, 16, 2, 2><<<dim3(32, 16, BATCH), 512, 0, stream>>>(
      A, wT + WO_L7, bs[7], flow, 512, 512, temp, def);
  // patches (overwrites the wT stash)
  patches_k<<<(BATCH * 256 * 64 * 64) / 256, 256, 0, stream>>>(x, def, out);
}

// Round 4
// 333.145 us; speedup vs baseline: 1.1030x; 1.1030x over previous
//
#include <hip/hip_runtime.h>
#include <hip/hip_bf16.h>

typedef __hip_bfloat16 bf16;
typedef unsigned short ushort_t;
typedef __attribute__((ext_vector_type(8))) short short8;
typedef __attribute__((ext_vector_type(4))) float float4v;

#define BATCH 4
#define HH 512
#define WW 512

// transposed-weight stash offsets (bf16 elems, at head of d_out; patches_k overwrites LAST)
#define WO_L0 0        // conv0 tap-packed [tl(4)][g(3)][o(32)][c(8)] = 3072
#define WO_L1 3072     // [ch][tap][32][32] = 9216
#define WO_L2 12288    // [ch][tap][64][32] = 18432
#define WO_L3 30720    // [ch2][tap][64][32] = 36864
#define WO_L4P 67584   // phase [ph4][ch2][tap][64][32] = 147456
#define WO_L5 215040   // [ch2][tap][32][32] = 18432
#define WO_L6P 233472  // phase [ph4][ch1][tap][32][32] = 36864
#define WO_L7 270336   // [ch][tap][16][32] = 4608
#define WO_L4U 274944  // unfused L4 [ch2][tap][64][32] = 36864 (edge path)
#define WO_L6U 311808  // unfused L6 [ch1][tap][32][32] = 9216  (edge path)

__device__ __forceinline__ ushort_t f2bfu(float f) {
  __hip_bfloat16 h = __float2bfloat16(f);
  union { __hip_bfloat16 h; ushort_t u; } c;
  c.h = h;
  return c.u;
}
__device__ __forceinline__ float bfu2f(ushort_t u) {
  return __uint_as_float(((unsigned)u) << 16);
}

// async global->LDS DMA, 16 B per lane; LDS dest = wave-uniform base + lane*16
__device__ __forceinline__ void dma16(void* lds, const void* g) {
  __builtin_amdgcn_global_load_lds(
      (const __attribute__((address_space(1))) unsigned int*)g,
      (__attribute__((address_space(3))) unsigned int*)lds, 16, 0, 0);
}

// bilinear x2 (half-pixel) row kernel: weight of src[i-1+u] in up[2i+dy-1+r].
__device__ __forceinline__ float upw(int k, int u) {
  int lo = k >> 1;
  float a = (k & 1) ? 0.25f : 0.75f;
  float b = (k & 1) ? 0.75f : 0.25f;
  return (u == lo) ? a : (u == lo + 1) ? b : 0.0f;
}

// ---------------------------------------------------------------------------
// Weight prep. Jobs:
//  0        : conv0 tap-packed  [tl][g][o][c8]  (k = tl*8+c, tap = g*4+tl)
//  4, 6     : phase-folded upsample+conv weights [ph][ch][tap][OP][32]
//  1,2,3,5,7: standard per-chunk [ch][tap][OP][32]
//  8, 9     : UNFUSED L4/L6 per-chunk [ch][tap][OP][32] (edge path)
// ---------------------------------------------------------------------------
struct WP { const float* w[8]; };

__global__ __launch_bounds__(256) void prep_w(WP wp, bf16* __restrict__ dst) {
  const int job = blockIdx.y;
  const int e = blockIdx.x * 256 + threadIdx.x;
  if (job == 0) {
    if (e >= 3072) return;
    int c = e & 7;
    int o = (e >> 3) & 31;
    int g = (e >> 8) % 3;
    int tl = (e >> 8) / 3;
    int tap = g * 4 + tl;
    float v = 0.0f;
    if (tap < 9 && c < 3) v = wp.w[0][(o * 3 + c) * 9 + tap];
    dst[WO_L0 + e] = __float2bfloat16(v);
    return;
  }
  if (job == 4 || job == 6) {
    const int O = (job == 4) ? 64 : 32;
    const int I = O;
    const int NCH = I >> 5;
    const int n = 4 * NCH * 9 * O * 32;
    if (e >= n) return;
    int ic = e & 31;
    int o = (e >> 5) % O;
    int tap = (e / (32 * O)) % 9;
    int ch = (e / (9 * 32 * O)) % NCH;
    int ph = e / (NCH * 9 * 32 * O);
    int i = ch * 32 + ic;
    int u = tap / 3, v2 = tap - u * 3;
    int dy = ph >> 1, dx = ph & 1;
    const float* w = wp.w[job];
    float acc = 0.0f;
#pragma unroll
    for (int r = 0; r < 3; ++r) {
      float ry = upw(r + dy, u);
#pragma unroll
      for (int s = 0; s < 3; ++s)
        acc += w[(o * I + i) * 9 + r * 3 + s] * ry * upw(s + dx, v2);
    }
    dst[((job == 4) ? WO_L4P : WO_L6P) + e] = __float2bfloat16(acc);
    return;
  }
  int O, I, OP, off;
  const float* w;
  if (job == 1)      { O = 32; I = 32; OP = 32; off = WO_L1; w = wp.w[1]; }
  else if (job == 2) { O = 64; I = 32; OP = 64; off = WO_L2; w = wp.w[2]; }
  else if (job == 3) { O = 64; I = 64; OP = 64; off = WO_L3; w = wp.w[3]; }
  else if (job == 5) { O = 32; I = 64; OP = 32; off = WO_L5; w = wp.w[5]; }
  else if (job == 7) { O = 2;  I = 32; OP = 16; off = WO_L7; w = wp.w[7]; }
  else if (job == 8) { O = 64; I = 64; OP = 64; off = WO_L4U; w = wp.w[4]; }
  else               { O = 32; I = 32; OP = 32; off = WO_L6U; w = wp.w[6]; }
  const int NCH = I >> 5;
  const int n = NCH * 9 * OP * 32;
  if (e >= n) return;
  int ic = e & 31;
  int o = (e >> 5) % OP;
  int tap = (e / (32 * OP)) % 9;
  int ch = e / (9 * 32 * OP);
  int i = ch * 32 + ic;
  float v = 0.0f;
  if (o < O) v = w[(o * I + i) * 9 + tap];
  dst[off + e] = __float2bfloat16(v);
}

// ---------------------------------------------------------------------------
// pack_x: NCHW f32 (3ch) -> NHWC-8 bf16 (ch 3..7 zero)
// ---------------------------------------------------------------------------
__global__ __launch_bounds__(256) void pack_x(const float* __restrict__ x,
                                              bf16* __restrict__ xp) {
  int i = blockIdx.x * 256 + threadIdx.x;
  if (i >= BATCH * HH * WW) return;
  int b = i / (HH * WW);
  int px = i - b * (HH * WW);
  union { uint4 v; ushort_t s[8]; } o;
  o.v = make_uint4(0, 0, 0, 0);
  const float* p = x + (long)b * 3 * HH * WW + px;
  o.s[0] = f2bfu(p[0]);
  o.s[1] = f2bfu(p[HH * WW]);
  o.s[2] = f2bfu(p[2 * HH * WW]);
  *(uint4*)&xp[(long)i * 8] = o.v;
}

// ---------------------------------------------------------------------------
// conv0: tap-packed K (4 taps x 8ch = K32). 8 waves, 32(t) x 16(w) tile.
// ---------------------------------------------------------------------------
__global__ __launch_bounds__(512) void conv0_k(
    const bf16* __restrict__ xp, const bf16* __restrict__ wt,
    const float* __restrict__ bias, bf16* __restrict__ out) {
  __shared__ alignas(16) bf16 in_lds[612 * 8];  // 34x18 halo x 8ch
  __shared__ alignas(16) bf16 w_lds[3072];
  const int tid = threadIdx.x;
  const int lane = tid & 63;
  const int wid = tid >> 6;  // 0..7
  const int lm = lane & 15;
  const int quad = lane >> 4;
  const int x0 = blockIdx.x * 16, y0 = blockIdx.y * 32;
  const int b = blockIdx.z;

#pragma unroll
  for (int k = 0; k < 2; ++k) {
    int u = tid + k * 512;
    if (u < 612) {
      int hy = u / 18, hx = u - hy * 18;
      int gy = y0 - 1 + hy, gx = x0 - 1 + hx;
      uint4 v = make_uint4(0, 0, 0, 0);
      if (gy >= 0 && gy < HH && gx >= 0 && gx < WW)
        v = *(const uint4*)(xp + (((long)b * HH + gy) * WW + gx) * 8);
      *(uint4*)&in_lds[u * 8] = v;
    }
  }
  if (tid < 384) *(uint4*)&w_lds[tid * 8] = *(const uint4*)(wt + tid * 8);
  __syncthreads();

  float4v acc[2][4];
#pragma unroll
  for (int mt = 0; mt < 2; ++mt) {
    float4v bv = *(const float4v*)(bias + mt * 16 + quad * 4);
#pragma unroll
    for (int nt = 0; nt < 4; ++nt) acc[mt][nt] = bv;
  }

#pragma unroll
  for (int g = 0; g < 3; ++g) {
    int tap = g * 4 + quad;
    if (tap > 8) tap = 8;  // clamped taps have zero A-weights
    int r = (tap * 11) >> 5;
    int s = tap - r * 3;
    short8 afrag[2], bfrag[4];
#pragma unroll
    for (int mt = 0; mt < 2; ++mt)
      afrag[mt] = *(const short8*)&w_lds[quad * 768 + (g * 32 + mt * 16 + lm) * 8];
#pragma unroll
    for (int nt = 0; nt < 4; ++nt) {
      int py = 4 * wid + nt;
      bfrag[nt] = *(const short8*)&in_lds[((py + r) * 18 + lm + s) * 8];
    }
#pragma unroll
    for (int mt = 0; mt < 2; ++mt)
#pragma unroll
      for (int nt = 0; nt < 4; ++nt)
        acc[mt][nt] = __builtin_amdgcn_mfma_f32_16x16x32_bf16(
            afrag[mt], bfrag[nt], acc[mt][nt], 0, 0, 0);
  }

#pragma unroll
  for (int mt = 0; mt < 2; ++mt)
#pragma unroll
    for (int nt = 0; nt < 4; ++nt) {
      int gy = y0 + 4 * wid + nt, gx = x0 + lm;
      union { uint2 v; ushort_t s2[4]; } pk;
#pragma unroll
      for (int r2 = 0; r2 < 4; ++r2) pk.s2[r2] = f2bfu(fmaxf(acc[mt][nt][r2], 0.0f));
      *(uint2*)&out[(((long)b * HH + gy) * WW + gx) * 32 + mt * 16 + quad * 4] = pk.v;
    }
}

// ---------------------------------------------------------------------------
// Implicit-GEMM 3x3 conv (pad 1), NHWC bf16. 8 waves, 32(t) x 16(w) tile.
// OUT_MODE: 0 = NHWC bf16 (+relu); 2 = flow NCHW f32 (tanh) + fused deformed;
//           3 = NHWC bf16, fused relu + 2x2 maxpool.
// ---------------------------------------------------------------------------
template <int CIN, int COUT, int COUTR, int OUT_MODE>
__global__ __launch_bounds__(512) void conv_mfma(
    const bf16* __restrict__ in, const bf16* __restrict__ wt,
    const float* __restrict__ bias, void* __restrict__ out_, int H, int W,
    const float* __restrict__ temp, float* __restrict__ def) {
  constexpr int MT = COUT / 16;
  constexpr int CK = 32;
  __shared__ alignas(16) bf16 in_lds[612 * CK];  // 34x18 halo x 32ch
  __shared__ alignas(16) bf16 w_lds[9 * COUT * CK];
  const int tid = threadIdx.x;
  const int lane = tid & 63;
  const int wid = tid >> 6;  // 0..7
  const int lm = lane & 15;
  const int quad = lane >> 4;
  const int x0 = blockIdx.x * 16;
  const int y0 = blockIdx.y * 32;
  const int b = blockIdx.z;

  float4v acc[MT][4];
#pragma unroll
  for (int mt = 0; mt < MT; ++mt) {
    float4v bv;
    if constexpr (COUTR == COUT) {
      bv = *(const float4v*)(bias + mt * 16 + quad * 4);
    } else {
#pragma unroll
      for (int r = 0; r < 4; ++r) {
        int co = mt * 16 + quad * 4 + r;
        bv[r] = (co < COUTR) ? bias[co] : 0.0f;
      }
    }
#pragma unroll
    for (int nt = 0; nt < 4; ++nt) acc[mt][nt] = bv;
  }

  const bool interior =
      (x0 >= 1) && (x0 + 16 <= W - 1) && (y0 >= 1) && (y0 + 32 <= H - 1);
  for (int c0 = 0; c0 < CIN; c0 += CK) {
    if (interior) {
      for (int r = wid; r < 34; r += 8) {
        int gy = y0 - 1 + r;
        const bf16* gsrc = in + (((long)b * H + gy) * W + x0) * CIN + c0 +
                           (lane >> 2) * CIN + (lane & 3) * 8;
        dma16(&in_lds[(r * 18 + 1) * CK], gsrc);
      }
      if (tid < 272) {
        int r = tid >> 3;
        int side = (tid >> 2) & 1;
        int seg = tid & 3;
        int gx = side ? (x0 + 16) : (x0 - 1);
        int gy = y0 - 1 + r;
        uint4 v = *(const uint4*)(in + (((long)b * H + gy) * W + gx) * CIN +
                                  c0 + seg * 8);
        *(uint4*)&in_lds[(r * 18 + (side ? 17 : 0)) * CK + seg * 8] = v;
      }
    } else {
      for (int u = tid; u < 612 * 4; u += 512) {
        int px = u >> 2;
        int seg = u & 3;
        int hy = px / 18, hx = px - hy * 18;
        int gy = y0 - 1 + hy, gx = x0 - 1 + hx;
        uint4 v = make_uint4(0, 0, 0, 0);
        if (gy >= 0 && gy < H && gx >= 0 && gx < W)
          v = *(const uint4*)(in + (((long)b * H + gy) * W + gx) * CIN + c0 +
                              seg * 8);
        *(uint4*)&in_lds[px * CK + seg * 8] = v;
      }
    }
    {
      const char* wsrc = (const char*)(wt + (size_t)(c0 >> 5) * 9 * COUT * CK);
      constexpr int WCH = 9 * COUT * CK * 2 / 1024;
      for (int j = wid; j < WCH; j += 8)
        dma16((char*)w_lds + j * 1024, wsrc + j * 1024 + lane * 16);
    }
    __syncthreads();

#pragma unroll
    for (int tap = 0; tap < 9; ++tap) {
      const int r = tap / 3, s = tap - r * 3;
      short8 afrag[MT], bfrag[4];
#pragma unroll
      for (int mt = 0; mt < MT; ++mt)
        afrag[mt] =
            *(const short8*)&w_lds[(tap * COUT + mt * 16 + lm) * CK + quad * 8];
#pragma unroll
      for (int nt = 0; nt < 4; ++nt) {
        int py = 4 * wid + nt;
        bfrag[nt] =
            *(const short8*)&in_lds[((py + r) * 18 + lm + s) * CK + quad * 8];
      }
#pragma unroll
      for (int mt = 0; mt < MT; ++mt)
#pragma unroll
        for (int nt = 0; nt < 4; ++nt)
          acc[mt][nt] = __builtin_amdgcn_mfma_f32_16x16x32_bf16(
              afrag[mt], bfrag[nt], acc[mt][nt], 0, 0, 0);
    }
    __syncthreads();
  }

  if constexpr (OUT_MODE == 3) {
    bf16* out = (bf16*)out_;
    const int Ho = H >> 1, Wo = W >> 1;
#pragma unroll
    for (int mt = 0; mt < MT; ++mt) {
#pragma unroll
      for (int g = 0; g < 2; ++g) {
        float4v m;
#pragma unroll
        for (int r = 0; r < 4; ++r)
          m[r] = fmaxf(fmaxf(acc[mt][2 * g][r], acc[mt][2 * g + 1][r]), 0.0f);
#pragma unroll
        for (int r = 0; r < 4; ++r) m[r] = fmaxf(m[r], __shfl_xor(m[r], 1, 64));
        if ((lm & 1) == 0) {
          int pyo = (y0 >> 1) + 2 * wid + g;
          int pxo = (x0 >> 1) + (lm >> 1);
          union { uint2 v; ushort_t s[4]; } pk;
#pragma unroll
          for (int r = 0; r < 4; ++r) pk.s[r] = f2bfu(m[r]);
          *(uint2*)&out[(((long)b * Ho + pyo) * Wo + pxo) * COUT + mt * 16 +
                        quad * 4] = pk.v;
        }
      }
    }
  } else {
#pragma unroll
    for (int mt = 0; mt < MT; ++mt) {
#pragma unroll
      for (int nt = 0; nt < 4; ++nt) {
        int gy = y0 + 4 * wid + nt;
        int gx = x0 + lm;
        float4v v = acc[mt][nt];
        if constexpr (OUT_MODE == 0) {
          bf16* out = (bf16*)out_;
          union { uint2 v; ushort_t s[4]; } pk;
#pragma unroll
          for (int r = 0; r < 4; ++r) pk.s[r] = f2bfu(fmaxf(v[r], 0.0f));
          *(uint2*)&out[(((long)b * H + gy) * W + gx) * COUT + mt * 16 +
                        quad * 4] = pk.v;
        } else {
          float* out = (float*)out_;
          if (quad == 0) {
            float fx = tanhf(v[0]);
            float fy = tanhf(v[1]);
            out[(((long)b * 2 + 0) * H + gy) * (long)W + gx] = fx;
            out[(((long)b * 2 + 1) * H + gy) * (long)W + gx] = fy;
            float T = temp[0];
            float2 d;
            d.x = -1.0f + gx * (2.0f / 511.0f) + fx * T;
            d.y = -1.0f + gy * (2.0f / 511.0f) + fy * T;
            *(float2*)&def[(((long)b * HH + gy) * WW + gx) * 2] = d;
          }
        }
      }
    }
  }
}

// ---------------------------------------------------------------------------
// conv_up: fused (x2 bilinear upsample -> 3x3 conv -> relu).
// Bulk blocks (blockIdx.x < nx*ny): phase-conv on HALF-res grid with folded
//   weights; 8 waves, 32x16 src tile = 64x32 output. Stores SKIP the 16-px
//   output border band.
// Edge blocks (blockIdx.x >= nx*ny): exact fused upsample-conv (on-the-fly
//   bilinear staging, zero pad, src clamp) for perimeter 16x16 output tiles;
//   they exclusively own the border band.  Runs concurrently with bulk.
// PSPLIT: blockIdx.z = b*4+ph (conv4, CIN=64); else z=b, loop ph 0..3.
// ---------------------------------------------------------------------------
template <int CIN, int COUT, bool PSPLIT>
__global__ __launch_bounds__(512) void conv_up(
    const bf16* __restrict__ in, const bf16* __restrict__ wtP,
    const bf16* __restrict__ wtU, const float* __restrict__ bias,
    bf16* __restrict__ out, int Ho, int Wo) {
  constexpr int MT = COUT / 16;
  constexpr int CK = 32;
  __shared__ alignas(16) bf16 in_lds[612 * CK];
  __shared__ alignas(16) bf16 w_lds[9 * COUT * CK];
  const int tid = threadIdx.x;
  const int lane = tid & 63;
  const int wid = tid >> 6;
  const int lm = lane & 15;
  const int quad = lane >> 4;
  const int Hs = Ho >> 1, Ws = Wo >> 1;
  const int nx = Ws >> 4, ny = Hs >> 5;
  const int bulkN = nx * ny;
  const int b = PSPLIT ? (blockIdx.z >> 2) : blockIdx.z;
  const int ph0 = PSPLIT ? (blockIdx.z & 3) : 0;
  const int t = blockIdx.x;

  if (t >= bulkN) {
    // ================= edge path (exact, owns 16-px border band) ==========
    if (PSPLIT && ph0 != 0) return;
    const int G = Wo >> 4;
    int e = t - bulkN;
    int tx, ty;
    if (e < G) { ty = 0; tx = e; }
    else if (e < 2 * G) { ty = G - 1; tx = e - G; }
    else { int u = e - 2 * G; ty = 1 + (u >> 1); tx = (u & 1) ? (G - 1) : 0; }
    const int x0 = tx * 16, y0 = ty * 16;

    float4v acc[MT][4];
#pragma unroll
    for (int mt = 0; mt < MT; ++mt) {
      float4v bv = *(const float4v*)(bias + mt * 16 + quad * 4);
#pragma unroll
      for (int nt = 0; nt < 4; ++nt) acc[mt][nt] = bv;
    }

    for (int c0 = 0; c0 < CIN; c0 += CK) {
      for (int u = tid; u < 324 * 4; u += 512) {
        int px = u >> 2;
        int seg = u & 3;
        int hy = px / 18, hx = px - hy * 18;
        int gy = y0 - 1 + hy, gx = x0 - 1 + hx;
        uint4 o = make_uint4(0, 0, 0, 0);
        if (gy >= 0 && gy < Ho && gx >= 0 && gx < Wo) {
          int ys = (gy >> 1) - ((gy & 1) ? 0 : 1);
          int xs = (gx >> 1) - ((gx & 1) ? 0 : 1);
          float wy = (gy & 1) ? 0.25f : 0.75f;
          float wx = (gx & 1) ? 0.25f : 0.75f;
          int y0c = max(ys, 0), y1c = min(ys + 1, Hs - 1);
          int x0c = max(xs, 0), x1c = min(xs + 1, Ws - 1);
          const bf16* p = in + ((long)b * Hs * Ws) * CIN + c0 + seg * 8;
          union { uint4 v; ushort_t s[8]; } a00, a01, a10, a11, r;
          a00.v = *(const uint4*)(p + ((long)y0c * Ws + x0c) * CIN);
          a01.v = *(const uint4*)(p + ((long)y0c * Ws + x1c) * CIN);
          a10.v = *(const uint4*)(p + ((long)y1c * Ws + x0c) * CIN);
          a11.v = *(const uint4*)(p + ((long)y1c * Ws + x1c) * CIN);
#pragma unroll
          for (int j = 0; j < 8; ++j) {
            float f = (1.0f - wy) * ((1.0f - wx) * bfu2f(a00.s[j]) +
                                     wx * bfu2f(a01.s[j])) +
                      wy * ((1.0f - wx) * bfu2f(a10.s[j]) +
                            wx * bfu2f(a11.s[j]));
            r.s[j] = f2bfu(f);
          }
          o = r.v;
        }
        *(uint4*)&in_lds[px * CK + seg * 8] = o;
      }
      {
        const char* wsrc = (const char*)(wtU + (size_t)(c0 >> 5) * 9 * COUT * CK);
        constexpr int WCH = 9 * COUT * CK * 2 / 1024;
        for (int j = wid; j < WCH; j += 8)
          dma16((char*)w_lds + j * 1024, wsrc + j * 1024 + lane * 16);
      }
      __syncthreads();
      if (wid < 4) {
#pragma unroll
        for (int tap = 0; tap < 9; ++tap) {
          const int r = tap / 3, s = tap - r * 3;
          short8 afrag[MT], bfrag[4];
#pragma unroll
          for (int mt = 0; mt < MT; ++mt)
            afrag[mt] =
                *(const short8*)&w_lds[(tap * COUT + mt * 16 + lm) * CK + quad * 8];
#pragma unroll
          for (int nt = 0; nt < 4; ++nt) {
            int py = 4 * wid + nt;
            bfrag[nt] =
                *(const short8*)&in_lds[((py + r) * 18 + lm + s) * CK + quad * 8];
          }
#pragma unroll
          for (int mt = 0; mt < MT; ++mt)
#pragma unroll
            for (int nt = 0; nt < 4; ++nt)
              acc[mt][nt] = __builtin_amdgcn_mfma_f32_16x16x32_bf16(
                  afrag[mt], bfrag[nt], acc[mt][nt], 0, 0, 0);
        }
      }
      __syncthreads();
    }
    if (wid < 4) {
#pragma unroll
      for (int mt = 0; mt < MT; ++mt)
#pragma unroll
        for (int nt = 0; nt < 4; ++nt) {
          int gy = y0 + 4 * wid + nt;
          int gx = x0 + lm;
          union { uint2 v; ushort_t s[4]; } pk;
#pragma unroll
          for (int r = 0; r < 4; ++r)
            pk.s[r] = f2bfu(fmaxf(acc[mt][nt][r], 0.0f));
          *(uint2*)&out[(((long)b * Ho + gy) * Wo + gx) * COUT + mt * 16 +
                        quad * 4] = pk.v;
        }
    }
    return;
  }

  // ================== bulk path (phase conv, folded weights) ==============
  const int bx = t % nx, by = t / nx;
  const int xs0 = bx * 16, ys0 = by * 32;
  const bool interior = (bx >= 1) && (bx < nx - 1) && (by >= 1) && (by < ny - 1);
  const int phEnd = PSPLIT ? ph0 + 1 : 4;

  for (int ph = ph0; ph < phEnd; ++ph) {
    float4v acc[MT][4];
#pragma unroll
    for (int mt = 0; mt < MT; ++mt) {
      float4v bv = *(const float4v*)(bias + mt * 16 + quad * 4);
#pragma unroll
      for (int nt = 0; nt < 4; ++nt) acc[mt][nt] = bv;
    }
    for (int c0 = 0; c0 < CIN; c0 += CK) {
      if (ph == ph0 || CIN > CK) {
        if (interior) {
          for (int r = wid; r < 34; r += 8) {
            int gy = ys0 - 1 + r;
            const bf16* gsrc = in + (((long)b * Hs + gy) * Ws + xs0) * CIN +
                               c0 + (lane >> 2) * CIN + (lane & 3) * 8;
            dma16(&in_lds[(r * 18 + 1) * CK], gsrc);
          }
          if (tid < 272) {
            int r = tid >> 3;
            int side = (tid >> 2) & 1;
            int seg = tid & 3;
            int gx = side ? (xs0 + 16) : (xs0 - 1);
            int gy = ys0 - 1 + r;
            uint4 v = *(const uint4*)(in + (((long)b * Hs + gy) * Ws + gx) * CIN +
                                      c0 + seg * 8);
            *(uint4*)&in_lds[(r * 18 + (side ? 17 : 0)) * CK + seg * 8] = v;
          }
        } else {
          for (int u = tid; u < 612 * 4; u += 512) {
            int px = u >> 2;
            int seg = u & 3;
            int hy = px / 18, hx = px - hy * 18;
            int sy = min(max(ys0 - 1 + hy, 0), Hs - 1);
            int sx = min(max(xs0 - 1 + hx, 0), Ws - 1);
            uint4 v = *(const uint4*)(in + (((long)b * Hs + sy) * Ws + sx) * CIN +
                                      c0 + seg * 8);
            *(uint4*)&in_lds[px * CK + seg * 8] = v;
          }
        }
      }
      {
        const char* wsrc = (const char*)(wtP + (size_t)(ph * (CIN / CK) + (c0 >> 5)) *
                                                  9 * COUT * CK);
        constexpr int WCH = 9 * COUT * CK * 2 / 1024;
        for (int j = wid; j < WCH; j += 8)
          dma16((char*)w_lds + j * 1024, wsrc + j * 1024 + lane * 16);
      }
      __syncthreads();
#pragma unroll
      for (int tap = 0; tap < 9; ++tap) {
        const int r = tap / 3, s = tap - r * 3;
        short8 afrag[MT], bfrag[4];
#pragma unroll
        for (int mt = 0; mt < MT; ++mt)
          afrag[mt] =
              *(const short8*)&w_lds[(tap * COUT + mt * 16 + lm) * CK + quad * 8];
#pragma unroll
        for (int nt = 0; nt < 4; ++nt) {
          int py = 4 * wid + nt;
          bfrag[nt] =
              *(const short8*)&in_lds[((py + r) * 18 + lm + s) * CK + quad * 8];
        }
#pragma unroll
        for (int mt = 0; mt < MT; ++mt)
#pragma unroll
          for (int nt = 0; nt < 4; ++nt)
            acc[mt][nt] = __builtin_amdgcn_mfma_f32_16x16x32_bf16(
                afrag[mt], bfrag[nt], acc[mt][nt], 0, 0, 0);
      }
      __syncthreads();
    }
    const int dy = ph >> 1, dx = ph & 1;
#pragma unroll
    for (int mt = 0; mt < MT; ++mt)
#pragma unroll
      for (int nt = 0; nt < 4; ++nt) {
        int gy = 2 * (ys0 + 4 * wid + nt) + dy;
        int gx = 2 * (xs0 + lm) + dx;
        // border band owned by edge blocks
        if (gy >= 16 && gy < Ho - 16 && gx >= 16 && gx < Wo - 16) {
          union { uint2 v; ushort_t s2[4]; } pk;
#pragma unroll
          for (int r2 = 0; r2 < 4; ++r2)
            pk.s2[r2] = f2bfu(fmaxf(acc[mt][nt][r2], 0.0f));
          *(uint2*)&out[(((long)b * Ho + gy) * Wo + gx) * COUT + mt * 16 +
                        quad * 4] = pk.v;
        }
      }
  }
}

// ---------------------------------------------------------------------------
// patches: grid_sample bilinear, zeros padding -> out [B,256,3,64,64]
// ---------------------------------------------------------------------------
__global__ __launch_bounds__(256) void patches_k(const float* __restrict__ x,
                                                 const float* __restrict__ def,
                                                 float* __restrict__ out) {
  int i = blockIdx.x * 256 + threadIdx.x;
  int pj = i & 63;
  int t = i >> 6;
  int pi = t & 63;
  t >>= 6;
  int n = t & 255;
  int b = t >> 8;
  if (b >= BATCH) return;
  int hi = n >> 4, wi = n & 15;
  const float* dptr = def + (((long)b * HH + hi * 32) * WW + wi * 32) * 2;
  float cx = dptr[0], cy = dptr[1];
  float pgx = cx + (-1.0f + pj * (2.0f / 63.0f)) * 0.125f;
  float pgy = cy + (-1.0f + pi * (2.0f / 63.0f)) * 0.125f;
  float ix = ((pgx + 1.0f) * 512.0f - 1.0f) * 0.5f;
  float iy = ((pgy + 1.0f) * 512.0f - 1.0f) * 0.5f;
  float fx0 = floorf(ix), fy0 = floorf(iy);
  float wx1 = ix - fx0, wy1 = iy - fy0;
  int x0 = (int)fx0, y0 = (int)fy0;
  int x1 = x0 + 1, y1 = y0 + 1;
  bool vx0 = (x0 >= 0) && (x0 <= 511), vx1 = (x1 >= 0) && (x1 <= 511);
  bool vy0 = (y0 >= 0) && (y0 <= 511), vy1 = (y1 >= 0) && (y1 <= 511);
  int cx0 = min(max(x0, 0), 511), cx1 = min(max(x1, 0), 511);
  int cy0 = min(max(y0, 0), 511), cy1 = min(max(y1, 0), 511);
  float w00 = (1.0f - wx1) * (1.0f - wy1) * ((vx0 && vy0) ? 1.0f : 0.0f);
  float w01 = wx1 * (1.0f - wy1) * ((vx1 && vy0) ? 1.0f : 0.0f);
  float w10 = (1.0f - wx1) * wy1 * ((vx0 && vy1) ? 1.0f : 0.0f);
  float w11 = wx1 * wy1 * ((vx1 && vy1) ? 1.0f : 0.0f);
#pragma unroll
  for (int c = 0; c < 3; ++c) {
    const float* img = x + ((long)b * 3 + c) * (HH * WW);
    float v = img[cy0 * WW + cx0] * w00 + img[cy0 * WW + cx1] * w01 +
              img[cy1 * WW + cx0] * w10 + img[cy1 * WW + cx1] * w11;
    out[(((long)b * 256 + n) * 3 + c) * 4096 + pi * 64 + pj] = v;
  }
}

// ---------------------------------------------------------------------------

extern "C" void kernel_launch(void* const* d_in, const int* in_sizes, int n_in,
                              void* d_out, int out_size, void* d_ws,
                              size_t ws_size, hipStream_t stream) {
  const float* x = (const float*)d_in[0];
  WP wp;
  const float* bs[8];
  for (int i = 0; i < 8; ++i) {
    wp.w[i] = (const float*)d_in[1 + 2 * i];
    bs[i] = (const float*)d_in[2 + 2 * i];
  }
  const float* temp = (const float*)d_in[17];

  float* out = (float*)d_out;
  float* flow = out + 12582912;  // [B,2,512,512] f32
  float* def = out + 14680064;   // [B,512,512,2] f32
  bf16* wT = (bf16*)d_out;       // weight stash; patches_k overwrites LAST

  const size_t bufElems = (size_t)BATCH * 512 * 512 * 32;
  bf16* A = (bf16*)d_ws;
  bf16* Bf = A + bufElems;
  bf16* xp = Bf + bufElems;

  prep_w<<<dim3(576, 10), 256, 0, stream>>>(wp, wT);
  pack_x<<<(BATCH * HH * WW) / 256, 256, 0, stream>>>(x, xp);

  // conv0 (tap-packed): xp -> A [512,512,32]
  conv0_k<<<dim3(32, 16, BATCH), 512, 0, stream>>>(xp, wT + WO_L0, bs[0], A);
  // conv1 + relu + pool: A -> Bf [256,256,32]
  conv_mfma<32, 32, 32, 3><<<dim3(32, 16, BATCH), 512, 0, stream>>>(
      A, wT + WO_L1, bs[1], Bf, 512, 512, nullptr, nullptr);
  // conv2: Bf -> A [256,256,64]
  conv_mfma<32, 64, 64, 0><<<dim3(16, 8, BATCH), 512, 0, stream>>>(
      Bf, wT + WO_L2, bs[2], A, 256, 256, nullptr, nullptr);
  // conv3 + relu + pool: A -> Bf [128,128,64]
  conv_mfma<64, 64, 64, 3><<<dim3(16, 8, BATCH), 512, 0, stream>>>(
      A, wT + WO_L3, bs[3], Bf, 256, 256, nullptr, nullptr);
  // conv4 (phase-split up1 + fused edge): Bf(128² src) -> A [256,256,64]
  // bulk 8x4 tiles + 60 edge tiles; z = b*4+ph
  conv_up<64, 64, true><<<dim3(8 * 4 + 60, 1, 4 * BATCH), 512, 0, stream>>>(
      Bf, wT + WO_L4P, wT + WO_L4U, bs[4], A, 256, 256);
  // conv5: A -> Bf [256,256,32]
  conv_mfma<64, 32, 32, 0><<<dim3(16, 8, BATCH), 512, 0, stream>>>(
      A, wT + WO_L5, bs[5], Bf, 256, 256, nullptr, nullptr);
  // conv6 (phase up2 + fused edge): Bf(256² src) -> A [512,512,32]
  conv_up<32, 32, false><<<dim3(16 * 8 + 124, 1, BATCH), 512, 0, stream>>>(
      Bf, wT + WO_L6P, wT + WO_L6U, bs[6], A, 512, 512);
  // conv7 + tanh + fused deformed: A -> flow + def
  conv_mfma<32, 16, 2, 2><<<dim3(32, 16, BATCH), 512, 0, stream>>>(
      A, wT + WO_L7, bs[7], flow, 512, 512, temp, def);
  // patches (overwrites the wT stash)
  patches_k<<<(BATCH * 256 * 64 * 64) / 256, 256, 0, stream>>>(x, def, out);
}

// Round 5
// 318.205 us; speedup vs baseline: 1.1548x; 1.0469x over previous
//
#include <hip/hip_runtime.h>
#include <hip/hip_bf16.h>

typedef __hip_bfloat16 bf16;
typedef unsigned short ushort_t;
typedef __attribute__((ext_vector_type(8))) short short8;
typedef __attribute__((ext_vector_type(4))) float float4v;

#define BATCH 4
#define HH 512
#define WW 512

// transposed-weight stash offsets (bf16 elems, at head of d_out; patches_k overwrites LAST)
#define WO_L0 0        // conv0 tap-packed [tl(4)][g(3)][o(32)][c(8)] = 3072
#define WO_L1 3072     // [ch][tap][32][32] = 9216
#define WO_L2 12288    // [ch][tap][64][32] = 18432
#define WO_L3 30720    // [ch2][tap][64][32] = 36864
#define WO_L4P 67584   // phase [ph4][ch2][tap][64][32] = 147456
#define WO_L5 215040   // [ch2][tap][32][32] = 18432
#define WO_L6P 233472  // phase [ph4][ch1][tap][32][32] = 36864
#define WO_L7 270336   // [ch][tap][16][32] = 4608
#define WO_L4U 274944  // unfused L4 [ch2][tap][64][32] = 36864 (edge path)
#define WO_L6U 311808  // unfused L6 [ch1][tap][32][32] = 9216  (edge path)

__device__ __forceinline__ ushort_t f2bfu(float f) {
  __hip_bfloat16 h = __float2bfloat16(f);
  union { __hip_bfloat16 h; ushort_t u; } c;
  c.h = h;
  return c.u;
}
__device__ __forceinline__ float bfu2f(ushort_t u) {
  return __uint_as_float(((unsigned)u) << 16);
}

// async global->LDS DMA, 16 B per lane; LDS dest = wave-uniform base + lane*16
__device__ __forceinline__ void dma16(void* lds, const void* g) {
  __builtin_amdgcn_global_load_lds(
      (const __attribute__((address_space(1))) unsigned int*)g,
      (__attribute__((address_space(3))) unsigned int*)lds, 16, 0, 0);
}

// bilinear x2 (half-pixel) row kernel: weight of src[i-1+u] in up[2i+dy-1+r].
__device__ __forceinline__ float upw(int k, int u) {
  int lo = k >> 1;
  float a = (k & 1) ? 0.25f : 0.75f;
  float b = (k & 1) ? 0.75f : 0.25f;
  return (u == lo) ? a : (u == lo + 1) ? b : 0.0f;
}

// ---------------------------------------------------------------------------
// Weight prep. Jobs:
//  0        : conv0 tap-packed  [tl][g][o][c8]  (k = tl*8+c, tap = g*4+tl)
//  4, 6     : phase-folded upsample+conv weights [ph][ch][tap][OP][32]
//  1,2,3,5,7: standard per-chunk [ch][tap][OP][32]
//  8, 9     : UNFUSED L4/L6 per-chunk [ch][tap][OP][32] (edge path)
// ---------------------------------------------------------------------------
struct WP { const float* w[8]; };

__global__ __launch_bounds__(256) void prep_w(WP wp, bf16* __restrict__ dst) {
  const int job = blockIdx.y;
  const int e = blockIdx.x * 256 + threadIdx.x;
  if (job == 0) {
    if (e >= 3072) return;
    int c = e & 7;
    int o = (e >> 3) & 31;
    int g = (e >> 8) % 3;
    int tl = (e >> 8) / 3;
    int tap = g * 4 + tl;
    float v = 0.0f;
    if (tap < 9 && c < 3) v = wp.w[0][(o * 3 + c) * 9 + tap];
    dst[WO_L0 + e] = __float2bfloat16(v);
    return;
  }
  if (job == 4 || job == 6) {
    const int O = (job == 4) ? 64 : 32;
    const int I = O;
    const int NCH = I >> 5;
    const int n = 4 * NCH * 9 * O * 32;
    if (e >= n) return;
    int ic = e & 31;
    int o = (e >> 5) % O;
    int tap = (e / (32 * O)) % 9;
    int ch = (e / (9 * 32 * O)) % NCH;
    int ph = e / (NCH * 9 * 32 * O);
    int i = ch * 32 + ic;
    int u = tap / 3, v2 = tap - u * 3;
    int dy = ph >> 1, dx = ph & 1;
    const float* w = wp.w[job];
    float acc = 0.0f;
#pragma unroll
    for (int r = 0; r < 3; ++r) {
      float ry = upw(r + dy, u);
#pragma unroll
      for (int s = 0; s < 3; ++s)
        acc += w[(o * I + i) * 9 + r * 3 + s] * ry * upw(s + dx, v2);
    }
    dst[((job == 4) ? WO_L4P : WO_L6P) + e] = __float2bfloat16(acc);
    return;
  }
  int O, I, OP, off;
  const float* w;
  if (job == 1)      { O = 32; I = 32; OP = 32; off = WO_L1; w = wp.w[1]; }
  else if (job == 2) { O = 64; I = 32; OP = 64; off = WO_L2; w = wp.w[2]; }
  else if (job == 3) { O = 64; I = 64; OP = 64; off = WO_L3; w = wp.w[3]; }
  else if (job == 5) { O = 32; I = 64; OP = 32; off = WO_L5; w = wp.w[5]; }
  else if (job == 7) { O = 2;  I = 32; OP = 16; off = WO_L7; w = wp.w[7]; }
  else if (job == 8) { O = 64; I = 64; OP = 64; off = WO_L4U; w = wp.w[4]; }
  else               { O = 32; I = 32; OP = 32; off = WO_L6U; w = wp.w[6]; }
  const int NCH = I >> 5;
  const int n = NCH * 9 * OP * 32;
  if (e >= n) return;
  int ic = e & 31;
  int o = (e >> 5) % OP;
  int tap = (e / (32 * OP)) % 9;
  int ch = e / (9 * 32 * OP);
  int i = ch * 32 + ic;
  float v = 0.0f;
  if (o < O) v = w[(o * I + i) * 9 + tap];
  dst[off + e] = __float2bfloat16(v);
}

// ---------------------------------------------------------------------------
// pack_x: NCHW f32 (3ch) -> NHWC-8 bf16 (ch 3..7 zero)
// ---------------------------------------------------------------------------
__global__ __launch_bounds__(256) void pack_x(const float* __restrict__ x,
                                              bf16* __restrict__ xp) {
  int i = blockIdx.x * 256 + threadIdx.x;
  if (i >= BATCH * HH * WW) return;
  int b = i / (HH * WW);
  int px = i - b * (HH * WW);
  union { uint4 v; ushort_t s[8]; } o;
  o.v = make_uint4(0, 0, 0, 0);
  const float* p = x + (long)b * 3 * HH * WW + px;
  o.s[0] = f2bfu(p[0]);
  o.s[1] = f2bfu(p[HH * WW]);
  o.s[2] = f2bfu(p[2 * HH * WW]);
  *(uint4*)&xp[(long)i * 8] = o.v;
}

// ---------------------------------------------------------------------------
// conv01_k: FUSED conv0 (tap-packed, relu) + conv1 (3x3, relu, 2x2 maxpool).
// conv0 output never leaves LDS: per block, compute conv0 on the 34x18 halo
// grid needed by conv1's 32x16 output tile, with explicit ZERO at image-OOB
// halo px (preserves conv1's zero-padding), then conv1+pool from LDS.
// Saves the 64 MB A-write + 64 MB re-read and one dispatch.
// ---------------------------------------------------------------------------
__global__ __launch_bounds__(512) void conv01_k(
    const bf16* __restrict__ xp, const bf16* __restrict__ w0,
    const bf16* __restrict__ w1, const float* __restrict__ b0,
    const float* __restrict__ b1, bf16* __restrict__ out) {
  __shared__ alignas(16) bf16 xp_lds[720 * 8];    // 36x20 double-halo, 8ch
  __shared__ alignas(16) bf16 mid_lds[612 * 32];  // 34x18 conv0 out
  __shared__ alignas(16) bf16 w0_lds[3072];
  __shared__ alignas(16) bf16 w1_lds[9 * 32 * 32];
  const int tid = threadIdx.x;
  const int lane = tid & 63;
  const int wid = tid >> 6;
  const int lm = lane & 15;
  const int quad = lane >> 4;
  const int x0 = blockIdx.x * 16, y0 = blockIdx.y * 32;
  const int b = blockIdx.z;

  // stage xp double-halo 36x20 around (y0-2, x0-2), zero outside image
  for (int u = tid; u < 720; u += 512) {
    int hy = u / 20, hx = u - hy * 20;
    int gy = y0 - 2 + hy, gx = x0 - 2 + hx;
    uint4 v = make_uint4(0, 0, 0, 0);
    if (gy >= 0 && gy < HH && gx >= 0 && gx < WW)
      v = *(const uint4*)(xp + (((long)b * HH + gy) * WW + gx) * 8);
    *(uint4*)&xp_lds[u * 8] = v;
  }
  if (tid < 384) *(uint4*)&w0_lds[tid * 8] = *(const uint4*)(w0 + tid * 8);
  for (int j = wid; j < 18; j += 8)
    dma16((char*)w1_lds + j * 1024, (const char*)w1 + j * 1024 + lane * 16);
  __syncthreads();

  // ---- conv0 -> mid_lds (612 px; relu; zero where halo px is image-OOB) ----
  for (int t = wid; t < 39; t += 8) {
    int px = t * 16 + lm;              // 0..623; valid < 612
    int pxc = min(px, 611);            // clamp for safe LDS reads
    int hy = pxc / 18, hx = pxc - hy * 18;
    float4v acc0[2];
#pragma unroll
    for (int mt = 0; mt < 2; ++mt)
      acc0[mt] = *(const float4v*)(b0 + mt * 16 + quad * 4);
#pragma unroll
    for (int g = 0; g < 3; ++g) {
      int tap = g * 4 + quad;
      if (tap > 8) tap = 8;  // clamped taps have zero A-weights
      int r = (tap * 11) >> 5;
      int s = tap - r * 3;
      short8 bfr = *(const short8*)&xp_lds[((hy + r) * 20 + hx + s) * 8];
      short8 a0 = *(const short8*)&w0_lds[quad * 768 + (g * 32 + lm) * 8];
      short8 a1 = *(const short8*)&w0_lds[quad * 768 + (g * 32 + 16 + lm) * 8];
      acc0[0] = __builtin_amdgcn_mfma_f32_16x16x32_bf16(a0, bfr, acc0[0], 0, 0, 0);
      acc0[1] = __builtin_amdgcn_mfma_f32_16x16x32_bf16(a1, bfr, acc0[1], 0, 0, 0);
    }
    int gy = y0 - 1 + hy, gx = x0 - 1 + hx;
    bool inimg = (gy >= 0) && (gy < HH) && (gx >= 0) && (gx < WW);
    if (px < 612) {
#pragma unroll
      for (int mt = 0; mt < 2; ++mt) {
        union { uint2 v; ushort_t s2[4]; } pk;
#pragma unroll
        for (int r2 = 0; r2 < 4; ++r2)
          pk.s2[r2] = inimg ? f2bfu(fmaxf(acc0[mt][r2], 0.0f)) : (ushort_t)0;
        *(uint2*)&mid_lds[px * 32 + mt * 16 + quad * 4] = pk.v;
      }
    }
  }
  __syncthreads();

  // ---- conv1 from mid_lds + relu + 2x2 maxpool -> out [256,256,32] ----
  float4v acc[2][4];
#pragma unroll
  for (int mt = 0; mt < 2; ++mt) {
    float4v bv = *(const float4v*)(b1 + mt * 16 + quad * 4);
#pragma unroll
    for (int nt = 0; nt < 4; ++nt) acc[mt][nt] = bv;
  }
#pragma unroll
  for (int tap = 0; tap < 9; ++tap) {
    const int r = tap / 3, s = tap - r * 3;
    short8 afrag[2], bfrag[4];
#pragma unroll
    for (int mt = 0; mt < 2; ++mt)
      afrag[mt] = *(const short8*)&w1_lds[(tap * 32 + mt * 16 + lm) * 32 + quad * 8];
#pragma unroll
    for (int nt = 0; nt < 4; ++nt) {
      int py = 4 * wid + nt;
      bfrag[nt] = *(const short8*)&mid_lds[((py + r) * 18 + lm + s) * 32 + quad * 8];
    }
#pragma unroll
    for (int mt = 0; mt < 2; ++mt)
#pragma unroll
      for (int nt = 0; nt < 4; ++nt)
        acc[mt][nt] = __builtin_amdgcn_mfma_f32_16x16x32_bf16(
            afrag[mt], bfrag[nt], acc[mt][nt], 0, 0, 0);
  }
  const int Ho = HH >> 1, Wo = WW >> 1;
#pragma unroll
  for (int mt = 0; mt < 2; ++mt) {
#pragma unroll
    for (int g = 0; g < 2; ++g) {
      float4v m;
#pragma unroll
      for (int r = 0; r < 4; ++r)
        m[r] = fmaxf(fmaxf(acc[mt][2 * g][r], acc[mt][2 * g + 1][r]), 0.0f);
#pragma unroll
      for (int r = 0; r < 4; ++r) m[r] = fmaxf(m[r], __shfl_xor(m[r], 1, 64));
      if ((lm & 1) == 0) {
        int pyo = (y0 >> 1) + 2 * wid + g;
        int pxo = (x0 >> 1) + (lm >> 1);
        union { uint2 v; ushort_t s[4]; } pk;
#pragma unroll
        for (int r = 0; r < 4; ++r) pk.s[r] = f2bfu(m[r]);
        *(uint2*)&out[(((long)b * Ho + pyo) * Wo + pxo) * 32 + mt * 16 +
                      quad * 4] = pk.v;
      }
    }
  }
}

// ---------------------------------------------------------------------------
// Implicit-GEMM 3x3 conv (pad 1), NHWC bf16. 8 waves, 32(t) x 16(w) tile.
// OUT_MODE: 0 = NHWC bf16 (+relu); 2 = flow NCHW f32 (tanh) + fused deformed;
//           3 = NHWC bf16, fused relu + 2x2 maxpool.
// ---------------------------------------------------------------------------
template <int CIN, int COUT, int COUTR, int OUT_MODE>
__global__ __launch_bounds__(512) void conv_mfma(
    const bf16* __restrict__ in, const bf16* __restrict__ wt,
    const float* __restrict__ bias, void* __restrict__ out_, int H, int W,
    const float* __restrict__ temp, float* __restrict__ def) {
  constexpr int MT = COUT / 16;
  constexpr int CK = 32;
  __shared__ alignas(16) bf16 in_lds[612 * CK];  // 34x18 halo x 32ch
  __shared__ alignas(16) bf16 w_lds[9 * COUT * CK];
  const int tid = threadIdx.x;
  const int lane = tid & 63;
  const int wid = tid >> 6;  // 0..7
  const int lm = lane & 15;
  const int quad = lane >> 4;
  const int x0 = blockIdx.x * 16;
  const int y0 = blockIdx.y * 32;
  const int b = blockIdx.z;

  float4v acc[MT][4];
#pragma unroll
  for (int mt = 0; mt < MT; ++mt) {
    float4v bv;
    if constexpr (COUTR == COUT) {
      bv = *(const float4v*)(bias + mt * 16 + quad * 4);
    } else {
#pragma unroll
      for (int r = 0; r < 4; ++r) {
        int co = mt * 16 + quad * 4 + r;
        bv[r] = (co < COUTR) ? bias[co] : 0.0f;
      }
    }
#pragma unroll
    for (int nt = 0; nt < 4; ++nt) acc[mt][nt] = bv;
  }

  const bool interior =
      (x0 >= 1) && (x0 + 16 <= W - 1) && (y0 >= 1) && (y0 + 32 <= H - 1);
  for (int c0 = 0; c0 < CIN; c0 += CK) {
    if (interior) {
      for (int r = wid; r < 34; r += 8) {
        int gy = y0 - 1 + r;
        const bf16* gsrc = in + (((long)b * H + gy) * W + x0) * CIN + c0 +
                           (lane >> 2) * CIN + (lane & 3) * 8;
        dma16(&in_lds[(r * 18 + 1) * CK], gsrc);
      }
      if (tid < 272) {
        int r = tid >> 3;
        int side = (tid >> 2) & 1;
        int seg = tid & 3;
        int gx = side ? (x0 + 16) : (x0 - 1);
        int gy = y0 - 1 + r;
        uint4 v = *(const uint4*)(in + (((long)b * H + gy) * W + gx) * CIN +
                                  c0 + seg * 8);
        *(uint4*)&in_lds[(r * 18 + (side ? 17 : 0)) * CK + seg * 8] = v;
      }
    } else {
      for (int u = tid; u < 612 * 4; u += 512) {
        int px = u >> 2;
        int seg = u & 3;
        int hy = px / 18, hx = px - hy * 18;
        int gy = y0 - 1 + hy, gx = x0 - 1 + hx;
        uint4 v = make_uint4(0, 0, 0, 0);
        if (gy >= 0 && gy < H && gx >= 0 && gx < W)
          v = *(const uint4*)(in + (((long)b * H + gy) * W + gx) * CIN + c0 +
                              seg * 8);
        *(uint4*)&in_lds[px * CK + seg * 8] = v;
      }
    }
    {
      const char* wsrc = (const char*)(wt + (size_t)(c0 >> 5) * 9 * COUT * CK);
      constexpr int WCH = 9 * COUT * CK * 2 / 1024;
      for (int j = wid; j < WCH; j += 8)
        dma16((char*)w_lds + j * 1024, wsrc + j * 1024 + lane * 16);
    }
    __syncthreads();

#pragma unroll
    for (int tap = 0; tap < 9; ++tap) {
      const int r = tap / 3, s = tap - r * 3;
      short8 afrag[MT], bfrag[4];
#pragma unroll
      for (int mt = 0; mt < MT; ++mt)
        afrag[mt] =
            *(const short8*)&w_lds[(tap * COUT + mt * 16 + lm) * CK + quad * 8];
#pragma unroll
      for (int nt = 0; nt < 4; ++nt) {
        int py = 4 * wid + nt;
        bfrag[nt] =
            *(const short8*)&in_lds[((py + r) * 18 + lm + s) * CK + quad * 8];
      }
#pragma unroll
      for (int mt = 0; mt < MT; ++mt)
#pragma unroll
        for (int nt = 0; nt < 4; ++nt)
          acc[mt][nt] = __builtin_amdgcn_mfma_f32_16x16x32_bf16(
              afrag[mt], bfrag[nt], acc[mt][nt], 0, 0, 0);
    }
    __syncthreads();
  }

  if constexpr (OUT_MODE == 3) {
    bf16* out = (bf16*)out_;
    const int Ho = H >> 1, Wo = W >> 1;
#pragma unroll
    for (int mt = 0; mt < MT; ++mt) {
#pragma unroll
      for (int g = 0; g < 2; ++g) {
        float4v m;
#pragma unroll
        for (int r = 0; r < 4; ++r)
          m[r] = fmaxf(fmaxf(acc[mt][2 * g][r], acc[mt][2 * g + 1][r]), 0.0f);
#pragma unroll
        for (int r = 0; r < 4; ++r) m[r] = fmaxf(m[r], __shfl_xor(m[r], 1, 64));
        if ((lm & 1) == 0) {
          int pyo = (y0 >> 1) + 2 * wid + g;
          int pxo = (x0 >> 1) + (lm >> 1);
          union { uint2 v; ushort_t s[4]; } pk;
#pragma unroll
          for (int r = 0; r < 4; ++r) pk.s[r] = f2bfu(m[r]);
          *(uint2*)&out[(((long)b * Ho + pyo) * Wo + pxo) * COUT + mt * 16 +
                        quad * 4] = pk.v;
        }
      }
    }
  } else {
#pragma unroll
    for (int mt = 0; mt < MT; ++mt) {
#pragma unroll
      for (int nt = 0; nt < 4; ++nt) {
        int gy = y0 + 4 * wid + nt;
        int gx = x0 + lm;
        float4v v = acc[mt][nt];
        if constexpr (OUT_MODE == 0) {
          bf16* out = (bf16*)out_;
          union { uint2 v; ushort_t s[4]; } pk;
#pragma unroll
          for (int r = 0; r < 4; ++r) pk.s[r] = f2bfu(fmaxf(v[r], 0.0f));
          *(uint2*)&out[(((long)b * H + gy) * W + gx) * COUT + mt * 16 +
                        quad * 4] = pk.v;
        } else {
          float* out = (float*)out_;
          if (quad == 0) {
            float fx = tanhf(v[0]);
            float fy = tanhf(v[1]);
            out[(((long)b * 2 + 0) * H + gy) * (long)W + gx] = fx;
            out[(((long)b * 2 + 1) * H + gy) * (long)W + gx] = fy;
            float T = temp[0];
            float2 d;
            d.x = -1.0f + gx * (2.0f / 511.0f) + fx * T;
            d.y = -1.0f + gy * (2.0f / 511.0f) + fy * T;
            *(float2*)&def[(((long)b * HH + gy) * WW + gx) * 2] = d;
          }
        }
      }
    }
  }
}

// ---------------------------------------------------------------------------
// conv_up: fused (x2 bilinear upsample -> 3x3 conv -> relu).
// Bulk blocks: phase-conv on HALF-res grid with folded weights; stores skip
//   the 16-px output border band.
// Edge blocks: exact fused upsample-conv for perimeter 16x16 output tiles.
// PSPLIT=true  (conv4, CIN=64): blockIdx.z = b*4+ph, single-buffered.
// PSPLIT=false (conv6, CIN=32==CK): phase loop with DOUBLE-BUFFERED weight
//   prefetch — input staged once, next phase's weights DMA'd during current
//   phase's MFMA, ONE barrier per phase.
// ---------------------------------------------------------------------------
template <int CIN, int COUT, bool PSPLIT>
__global__ __launch_bounds__(512) void conv_up(
    const bf16* __restrict__ in, const bf16* __restrict__ wtP,
    const bf16* __restrict__ wtU, const float* __restrict__ bias,
    bf16* __restrict__ out, int Ho, int Wo) {
  constexpr int MT = COUT / 16;
  constexpr int CK = 32;
  constexpr int WSZ = 9 * COUT * CK;
  constexpr int NWB = PSPLIT ? 1 : 2;
  __shared__ alignas(16) bf16 in_lds[612 * CK];
  __shared__ alignas(16) bf16 w_lds[NWB * WSZ];
  const int tid = threadIdx.x;
  const int lane = tid & 63;
  const int wid = tid >> 6;
  const int lm = lane & 15;
  const int quad = lane >> 4;
  const int Hs = Ho >> 1, Ws = Wo >> 1;
  const int nx = Ws >> 4, ny = Hs >> 5;
  const int bulkN = nx * ny;
  const int b = PSPLIT ? (blockIdx.z >> 2) : blockIdx.z;
  const int ph0 = PSPLIT ? (blockIdx.z & 3) : 0;
  const int t = blockIdx.x;

  if (t >= bulkN) {
    // ================= edge path (exact, owns 16-px border band) ==========
    if (PSPLIT && ph0 != 0) return;
    const int G = Wo >> 4;
    int e = t - bulkN;
    int tx, ty;
    if (e < G) { ty = 0; tx = e; }
    else if (e < 2 * G) { ty = G - 1; tx = e - G; }
    else { int u = e - 2 * G; ty = 1 + (u >> 1); tx = (u & 1) ? (G - 1) : 0; }
    const int x0 = tx * 16, y0 = ty * 16;

    float4v acc[MT][4];
#pragma unroll
    for (int mt = 0; mt < MT; ++mt) {
      float4v bv = *(const float4v*)(bias + mt * 16 + quad * 4);
#pragma unroll
      for (int nt = 0; nt < 4; ++nt) acc[mt][nt] = bv;
    }

    for (int c0 = 0; c0 < CIN; c0 += CK) {
      for (int u = tid; u < 324 * 4; u += 512) {
        int px = u >> 2;
        int seg = u & 3;
        int hy = px / 18, hx = px - hy * 18;
        int gy = y0 - 1 + hy, gx = x0 - 1 + hx;
        uint4 o = make_uint4(0, 0, 0, 0);
        if (gy >= 0 && gy < Ho && gx >= 0 && gx < Wo) {
          int ys = (gy >> 1) - ((gy & 1) ? 0 : 1);
          int xs = (gx >> 1) - ((gx & 1) ? 0 : 1);
          float wy = (gy & 1) ? 0.25f : 0.75f;
          float wx = (gx & 1) ? 0.25f : 0.75f;
          int y0c = max(ys, 0), y1c = min(ys + 1, Hs - 1);
          int x0c = max(xs, 0), x1c = min(xs + 1, Ws - 1);
          const bf16* p = in + ((long)b * Hs * Ws) * CIN + c0 + seg * 8;
          union { uint4 v; ushort_t s[8]; } a00, a01, a10, a11, r;
          a00.v = *(const uint4*)(p + ((long)y0c * Ws + x0c) * CIN);
          a01.v = *(const uint4*)(p + ((long)y0c * Ws + x1c) * CIN);
          a10.v = *(const uint4*)(p + ((long)y1c * Ws + x0c) * CIN);
          a11.v = *(const uint4*)(p + ((long)y1c * Ws + x1c) * CIN);
#pragma unroll
          for (int j = 0; j < 8; ++j) {
            float f = (1.0f - wy) * ((1.0f - wx) * bfu2f(a00.s[j]) +
                                     wx * bfu2f(a01.s[j])) +
                      wy * ((1.0f - wx) * bfu2f(a10.s[j]) +
                            wx * bfu2f(a11.s[j]));
            r.s[j] = f2bfu(f);
          }
          o = r.v;
        }
        *(uint4*)&in_lds[px * CK + seg * 8] = o;
      }
      {
        const char* wsrc = (const char*)(wtU + (size_t)(c0 >> 5) * WSZ);
        constexpr int WCH = WSZ * 2 / 1024;
        for (int j = wid; j < WCH; j += 8)
          dma16((char*)w_lds + j * 1024, wsrc + j * 1024 + lane * 16);
      }
      __syncthreads();
      if (wid < 4) {
#pragma unroll
        for (int tap = 0; tap < 9; ++tap) {
          const int r = tap / 3, s = tap - r * 3;
          short8 afrag[MT], bfrag[4];
#pragma unroll
          for (int mt = 0; mt < MT; ++mt)
            afrag[mt] =
                *(const short8*)&w_lds[(tap * COUT + mt * 16 + lm) * CK + quad * 8];
#pragma unroll
          for (int nt = 0; nt < 4; ++nt) {
            int py = 4 * wid + nt;
            bfrag[nt] =
                *(const short8*)&in_lds[((py + r) * 18 + lm + s) * CK + quad * 8];
          }
#pragma unroll
          for (int mt = 0; mt < MT; ++mt)
#pragma unroll
            for (int nt = 0; nt < 4; ++nt)
              acc[mt][nt] = __builtin_amdgcn_mfma_f32_16x16x32_bf16(
                  afrag[mt], bfrag[nt], acc[mt][nt], 0, 0, 0);
        }
      }
      __syncthreads();
    }
    if (wid < 4) {
#pragma unroll
      for (int mt = 0; mt < MT; ++mt)
#pragma unroll
        for (int nt = 0; nt < 4; ++nt) {
          int gy = y0 + 4 * wid + nt;
          int gx = x0 + lm;
          union { uint2 v; ushort_t s[4]; } pk;
#pragma unroll
          for (int r = 0; r < 4; ++r)
            pk.s[r] = f2bfu(fmaxf(acc[mt][nt][r], 0.0f));
          *(uint2*)&out[(((long)b * Ho + gy) * Wo + gx) * COUT + mt * 16 +
                        quad * 4] = pk.v;
        }
    }
    return;
  }

  // ================== bulk path (phase conv, folded weights) ==============
  const int bx = t % nx, by = t / nx;
  const int xs0 = bx * 16, ys0 = by * 32;
  const bool interior = (bx >= 1) && (bx < nx - 1) && (by >= 1) && (by < ny - 1);

  if constexpr (!PSPLIT) {
    // CIN == CK: input staged once, weights double-buffered across phases.
    static_assert(CIN == CK, "non-split bulk path assumes single K chunk");
    if (interior) {
      for (int r = wid; r < 34; r += 8) {
        int gy = ys0 - 1 + r;
        const bf16* gsrc = in + (((long)b * Hs + gy) * Ws + xs0) * CIN +
                           (lane >> 2) * CIN + (lane & 3) * 8;
        dma16(&in_lds[(r * 18 + 1) * CK], gsrc);
      }
      if (tid < 272) {
        int r = tid >> 3;
        int side = (tid >> 2) & 1;
        int seg = tid & 3;
        int gx = side ? (xs0 + 16) : (xs0 - 1);
        int gy = ys0 - 1 + r;
        uint4 v = *(const uint4*)(in + (((long)b * Hs + gy) * Ws + gx) * CIN +
                                  seg * 8);
        *(uint4*)&in_lds[(r * 18 + (side ? 17 : 0)) * CK + seg * 8] = v;
      }
    } else {
      for (int u = tid; u < 612 * 4; u += 512) {
        int px = u >> 2;
        int seg = u & 3;
        int hy = px / 18, hx = px - hy * 18;
        int sy = min(max(ys0 - 1 + hy, 0), Hs - 1);
        int sx = min(max(xs0 - 1 + hx, 0), Ws - 1);
        uint4 v = *(const uint4*)(in + (((long)b * Hs + sy) * Ws + sx) * CIN +
                                  seg * 8);
        *(uint4*)&in_lds[px * CK + seg * 8] = v;
      }
    }
    constexpr int WCH = WSZ * 2 / 1024;
    for (int j = wid; j < WCH; j += 8)
      dma16((char*)w_lds + j * 1024, (const char*)wtP + j * 1024 + lane * 16);
    __syncthreads();

    for (int ph = 0; ph < 4; ++ph) {
      const int cur = ph & 1;
      if (ph < 3) {
        const char* wsrc = (const char*)(wtP + (size_t)(ph + 1) * WSZ);
        char* wdst = (char*)w_lds + (cur ^ 1) * WSZ * 2;
        for (int j = wid; j < WCH; j += 8)
          dma16(wdst + j * 1024, wsrc + j * 1024 + lane * 16);
      }
      float4v acc[MT][4];
#pragma unroll
      for (int mt = 0; mt < MT; ++mt) {
        float4v bv = *(const float4v*)(bias + mt * 16 + quad * 4);
#pragma unroll
        for (int nt = 0; nt < 4; ++nt) acc[mt][nt] = bv;
      }
      const bf16* wb = w_lds + cur * WSZ;
#pragma unroll
      for (int tap = 0; tap < 9; ++tap) {
        const int r = tap / 3, s = tap - r * 3;
        short8 afrag[MT], bfrag[4];
#pragma unroll
        for (int mt = 0; mt < MT; ++mt)
          afrag[mt] =
              *(const short8*)&wb[(tap * COUT + mt * 16 + lm) * CK + quad * 8];
#pragma unroll
        for (int nt = 0; nt < 4; ++nt) {
          int py = 4 * wid + nt;
          bfrag[nt] =
              *(const short8*)&in_lds[((py + r) * 18 + lm + s) * CK + quad * 8];
        }
#pragma unroll
        for (int mt = 0; mt < MT; ++mt)
#pragma unroll
          for (int nt = 0; nt < 4; ++nt)
            acc[mt][nt] = __builtin_amdgcn_mfma_f32_16x16x32_bf16(
                afrag[mt], bfrag[nt], acc[mt][nt], 0, 0, 0);
      }
      const int dy = ph >> 1, dx = ph & 1;
#pragma unroll
      for (int mt = 0; mt < MT; ++mt)
#pragma unroll
        for (int nt = 0; nt < 4; ++nt) {
          int gy = 2 * (ys0 + 4 * wid + nt) + dy;
          int gx = 2 * (xs0 + lm) + dx;
          if (gy >= 16 && gy < Ho - 16 && gx >= 16 && gx < Wo - 16) {
            union { uint2 v; ushort_t s2[4]; } pk;
#pragma unroll
            for (int r2 = 0; r2 < 4; ++r2)
              pk.s2[r2] = f2bfu(fmaxf(acc[mt][nt][r2], 0.0f));
            *(uint2*)&out[(((long)b * Ho + gy) * Wo + gx) * COUT + mt * 16 +
                          quad * 4] = pk.v;
          }
        }
      __syncthreads();
    }
    return;
  }

  // PSPLIT bulk: one phase per block, multi-chunk K, single-buffered.
  const int ph = ph0;
  float4v acc[MT][4];
#pragma unroll
  for (int mt = 0; mt < MT; ++mt) {
    float4v bv = *(const float4v*)(bias + mt * 16 + quad * 4);
#pragma unroll
    for (int nt = 0; nt < 4; ++nt) acc[mt][nt] = bv;
  }
  for (int c0 = 0; c0 < CIN; c0 += CK) {
    if (interior) {
      for (int r = wid; r < 34; r += 8) {
        int gy = ys0 - 1 + r;
        const bf16* gsrc = in + (((long)b * Hs + gy) * Ws + xs0) * CIN +
                           c0 + (lane >> 2) * CIN + (lane & 3) * 8;
        dma16(&in_lds[(r * 18 + 1) * CK], gsrc);
      }
      if (tid < 272) {
        int r = tid >> 3;
        int side = (tid >> 2) & 1;
        int seg = tid & 3;
        int gx = side ? (xs0 + 16) : (xs0 - 1);
        int gy = ys0 - 1 + r;
        uint4 v = *(const uint4*)(in + (((long)b * Hs + gy) * Ws + gx) * CIN +
                                  c0 + seg * 8);
        *(uint4*)&in_lds[(r * 18 + (side ? 17 : 0)) * CK + seg * 8] = v;
      }
    } else {
      for (int u = tid; u < 612 * 4; u += 512) {
        int px = u >> 2;
        int seg = u & 3;
        int hy = px / 18, hx = px - hy * 18;
        int sy = min(max(ys0 - 1 + hy, 0), Hs - 1);
        int sx = min(max(xs0 - 1 + hx, 0), Ws - 1);
        uint4 v = *(const uint4*)(in + (((long)b * Hs + sy) * Ws + sx) * CIN +
                                  seg * 8);
        *(uint4*)&in_lds[px * CK + seg * 8] = v;
      }
    }
    {
      const char* wsrc = (const char*)(wtP + (size_t)(ph * (CIN / CK) + (c0 >> 5)) * WSZ);
      constexpr int WCH = WSZ * 2 / 1024;
      for (int j = wid; j < WCH; j += 8)
        dma16((char*)w_lds + j * 1024, wsrc + j * 1024 + lane * 16);
    }
    __syncthreads();
#pragma unroll
    for (int tap = 0; tap < 9; ++tap) {
      const int r = tap / 3, s = tap - r * 3;
      short8 afrag[MT], bfrag[4];
#pragma unroll
      for (int mt = 0; mt < MT; ++mt)
        afrag[mt] =
            *(const short8*)&w_lds[(tap * COUT + mt * 16 + lm) * CK + quad * 8];
#pragma unroll
      for (int nt = 0; nt < 4; ++nt) {
        int py = 4 * wid + nt;
        bfrag[nt] =
            *(const short8*)&in_lds[((py + r) * 18 + lm + s) * CK + quad * 8];
      }
#pragma unroll
      for (int mt = 0; mt < MT; ++mt)
#pragma unroll
        for (int nt = 0; nt < 4; ++nt)
          acc[mt][nt] = __builtin_amdgcn_mfma_f32_16x16x32_bf16(
              afrag[mt], bfrag[nt], acc[mt][nt], 0, 0, 0);
    }
    __syncthreads();
  }
  const int dy = ph >> 1, dx = ph & 1;
#pragma unroll
  for (int mt = 0; mt < MT; ++mt)
#pragma unroll
    for (int nt = 0; nt < 4; ++nt) {
      int gy = 2 * (ys0 + 4 * wid + nt) + dy;
      int gx = 2 * (xs0 + lm) + dx;
      if (gy >= 16 && gy < Ho - 16 && gx >= 16 && gx < Wo - 16) {
        union { uint2 v; ushort_t s2[4]; } pk;
#pragma unroll
        for (int r2 = 0; r2 < 4; ++r2)
          pk.s2[r2] = f2bfu(fmaxf(acc[mt][nt][r2], 0.0f));
        *(uint2*)&out[(((long)b * Ho + gy) * Wo + gx) * COUT + mt * 16 +
                      quad * 4] = pk.v;
      }
    }
}

// ---------------------------------------------------------------------------
// patches: grid_sample bilinear, zeros padding -> out [B,256,3,64,64]
// ---------------------------------------------------------------------------
__global__ __launch_bounds__(256) void patches_k(const float* __restrict__ x,
                                                 const float* __restrict__ def,
                                                 float* __restrict__ out) {
  int i = blockIdx.x * 256 + threadIdx.x;
  int pj = i & 63;
  int t = i >> 6;
  int pi = t & 63;
  t >>= 6;
  int n = t & 255;
  int b = t >> 8;
  if (b >= BATCH) return;
  int hi = n >> 4, wi = n & 15;
  const float* dptr = def + (((long)b * HH + hi * 32) * WW + wi * 32) * 2;
  float cx = dptr[0], cy = dptr[1];
  float pgx = cx + (-1.0f + pj * (2.0f / 63.0f)) * 0.125f;
  float pgy = cy + (-1.0f + pi * (2.0f / 63.0f)) * 0.125f;
  float ix = ((pgx + 1.0f) * 512.0f - 1.0f) * 0.5f;
  float iy = ((pgy + 1.0f) * 512.0f - 1.0f) * 0.5f;
  float fx0 = floorf(ix), fy0 = floorf(iy);
  float wx1 = ix - fx0, wy1 = iy - fy0;
  int x0 = (int)fx0, y0 = (int)fy0;
  int x1 = x0 + 1, y1 = y0 + 1;
  bool vx0 = (x0 >= 0) && (x0 <= 511), vx1 = (x1 >= 0) && (x1 <= 511);
  bool vy0 = (y0 >= 0) && (y0 <= 511), vy1 = (y1 >= 0) && (y1 <= 511);
  int cx0 = min(max(x0, 0), 511), cx1 = min(max(x1, 0), 511);
  int cy0 = min(max(y0, 0), 511), cy1 = min(max(y1, 0), 511);
  float w00 = (1.0f - wx1) * (1.0f - wy1) * ((vx0 && vy0) ? 1.0f : 0.0f);
  float w01 = wx1 * (1.0f - wy1) * ((vx1 && vy0) ? 1.0f : 0.0f);
  float w10 = (1.0f - wx1) * wy1 * ((vx0 && vy1) ? 1.0f : 0.0f);
  float w11 = wx1 * wy1 * ((vx1 && vy1) ? 1.0f : 0.0f);
#pragma unroll
  for (int c = 0; c < 3; ++c) {
    const float* img = x + ((long)b * 3 + c) * (HH * WW);
    float v = img[cy0 * WW + cx0] * w00 + img[cy0 * WW + cx1] * w01 +
              img[cy1 * WW + cx0] * w10 + img[cy1 * WW + cx1] * w11;
    out[(((long)b * 256 + n) * 3 + c) * 4096 + pi * 64 + pj] = v;
  }
}

// ---------------------------------------------------------------------------

extern "C" void kernel_launch(void* const* d_in, const int* in_sizes, int n_in,
                              void* d_out, int out_size, void* d_ws,
                              size_t ws_size, hipStream_t stream) {
  const float* x = (const float*)d_in[0];
  WP wp;
  const float* bs[8];
  for (int i = 0; i < 8; ++i) {
    wp.w[i] = (const float*)d_in[1 + 2 * i];
    bs[i] = (const float*)d_in[2 + 2 * i];
  }
  const float* temp = (const float*)d_in[17];

  float* out = (float*)d_out;
  float* flow = out + 12582912;  // [B,2,512,512] f32
  float* def = out + 14680064;   // [B,512,512,2] f32
  bf16* wT = (bf16*)d_out;       // weight stash; patches_k overwrites LAST

  const size_t bufElems = (size_t)BATCH * 512 * 512 * 32;
  bf16* A = (bf16*)d_ws;
  bf16* Bf = A + bufElems;
  bf16* xp = Bf + bufElems;

  prep_w<<<dim3(576, 10), 256, 0, stream>>>(wp, wT);
  pack_x<<<(BATCH * HH * WW) / 256, 256, 0, stream>>>(x, xp);

  // fused conv0+conv1 (+relu+pool): xp -> Bf [256,256,32]
  conv01_k<<<dim3(32, 16, BATCH), 512, 0, stream>>>(
      xp, wT + WO_L0, wT + WO_L1, bs[0], bs[1], Bf);
  // conv2: Bf -> A [256,256,64]
  conv_mfma<32, 64, 64, 0><<<dim3(16, 8, BATCH), 512, 0, stream>>>(
      Bf, wT + WO_L2, bs[2], A, 256, 256, nullptr, nullptr);
  // conv3 + relu + pool: A -> Bf [128,128,64]
  conv_mfma<64, 64, 64, 3><<<dim3(16, 8, BATCH), 512, 0, stream>>>(
      A, wT + WO_L3, bs[3], Bf, 256, 256, nullptr, nullptr);
  // conv4 (phase-split up1 + fused edge): Bf(128² src) -> A [256,256,64]
  conv_up<64, 64, true><<<dim3(8 * 4 + 60, 1, 4 * BATCH), 512, 0, stream>>>(
      Bf, wT + WO_L4P, wT + WO_L4U, bs[4], A, 256, 256);
  // conv5: A -> Bf [256,256,32]
  conv_mfma<64, 32, 32, 0><<<dim3(16, 8, BATCH), 512, 0, stream>>>(
      A, wT + WO_L5, bs[5], Bf, 256, 256, nullptr, nullptr);
  // conv6 (phase up2, w-prefetch dbuf + fused edge): Bf(256² src) -> A [512,512,32]
  conv_up<32, 32, false><<<dim3(16 * 8 + 124, 1, BATCH), 512, 0, stream>>>(
      Bf, wT + WO_L6P, wT + WO_L6U, bs[6], A, 512, 512);
  // conv7 + tanh + fused deformed: A -> flow + def
  conv_mfma<32, 16, 2, 2><<<dim3(32, 16, BATCH), 512, 0, stream>>>(
      A, wT + WO_L7, bs[7], flow, 512, 512, temp, def);
  // patches (overwrites the wT stash)
  patches_k<<<(BATCH * 256 * 64 * 64) / 256, 256, 0, stream>>>(x, def, out);
}

// Round 6
// 317.473 us; speedup vs baseline: 1.1574x; 1.0023x over previous
//
#include <hip/hip_runtime.h>
#include <hip/hip_bf16.h>

typedef __hip_bfloat16 bf16;
typedef unsigned short ushort_t;
typedef __attribute__((ext_vector_type(8))) short short8;
typedef __attribute__((ext_vector_type(4))) float float4v;

#define BATCH 4
#define HH 512
#define WW 512

// transposed-weight stash offsets (bf16 elems, at head of d_out; patches_k overwrites LAST)
#define WO_L0 0        // conv0 tap-packed [tl(4)][g(3)][o(32)][c(8)] = 3072
#define WO_L1 3072     // [ch][tap][32][32] = 9216
#define WO_L2 12288    // [ch][tap][64][32] = 18432
#define WO_L3 30720    // [ch2][tap][64][32] = 36864
#define WO_L4P 67584   // phase [ph4][ch2][tap][64][32] = 147456
#define WO_L5 215040   // [ch2][tap][32][32] = 18432
#define WO_L6P 233472  // phase [ph4][ch1][tap][32][32] = 36864
#define WO_L7 270336   // [ch][tap][16][32] = 4608
#define WO_L4U 274944  // unfused L4 [ch2][tap][64][32] = 36864 (edge path)
#define WO_L6U 311808  // unfused L6 [ch1][tap][32][32] = 9216  (edge path)

__device__ __forceinline__ ushort_t f2bfu(float f) {
  __hip_bfloat16 h = __float2bfloat16(f);
  union { __hip_bfloat16 h; ushort_t u; } c;
  c.h = h;
  return c.u;
}
__device__ __forceinline__ float bfu2f(ushort_t u) {
  return __uint_as_float(((unsigned)u) << 16);
}

// async global->LDS DMA, 16 B per lane; LDS dest = wave-uniform base + lane*16
__device__ __forceinline__ void dma16(void* lds, const void* g) {
  __builtin_amdgcn_global_load_lds(
      (const __attribute__((address_space(1))) unsigned int*)g,
      (__attribute__((address_space(3))) unsigned int*)lds, 16, 0, 0);
}

// bilinear x2 (half-pixel) row kernel: weight of src[i-1+u] in up[2i+dy-1+r].
__device__ __forceinline__ float upw(int k, int u) {
  int lo = k >> 1;
  float a = (k & 1) ? 0.25f : 0.75f;
  float b = (k & 1) ? 0.75f : 0.25f;
  return (u == lo) ? a : (u == lo + 1) ? b : 0.0f;
}

// ---------------------------------------------------------------------------
// Weight prep. Jobs:
//  0        : conv0 tap-packed  [tl][g][o][c8]  (k = tl*8+c, tap = g*4+tl)
//  4, 6     : phase-folded upsample+conv weights [ph][ch][tap][OP][32]
//  1,2,3,5,7: standard per-chunk [ch][tap][OP][32]
//  8, 9     : UNFUSED L4/L6 per-chunk [ch][tap][OP][32] (edge path)
// ---------------------------------------------------------------------------
struct WP { const float* w[8]; };

__global__ __launch_bounds__(256) void prep_w(WP wp, bf16* __restrict__ dst) {
  const int job = blockIdx.y;
  const int e = blockIdx.x * 256 + threadIdx.x;
  if (job == 0) {
    if (e >= 3072) return;
    int c = e & 7;
    int o = (e >> 3) & 31;
    int g = (e >> 8) % 3;
    int tl = (e >> 8) / 3;
    int tap = g * 4 + tl;
    float v = 0.0f;
    if (tap < 9 && c < 3) v = wp.w[0][(o * 3 + c) * 9 + tap];
    dst[WO_L0 + e] = __float2bfloat16(v);
    return;
  }
  if (job == 4 || job == 6) {
    const int O = (job == 4) ? 64 : 32;
    const int I = O;
    const int NCH = I >> 5;
    const int n = 4 * NCH * 9 * O * 32;
    if (e >= n) return;
    int ic = e & 31;
    int o = (e >> 5) % O;
    int tap = (e / (32 * O)) % 9;
    int ch = (e / (9 * 32 * O)) % NCH;
    int ph = e / (NCH * 9 * 32 * O);
    int i = ch * 32 + ic;
    int u = tap / 3, v2 = tap - u * 3;
    int dy = ph >> 1, dx = ph & 1;
    const float* w = wp.w[job];
    float acc = 0.0f;
#pragma unroll
    for (int r = 0; r < 3; ++r) {
      float ry = upw(r + dy, u);
#pragma unroll
      for (int s = 0; s < 3; ++s)
        acc += w[(o * I + i) * 9 + r * 3 + s] * ry * upw(s + dx, v2);
    }
    dst[((job == 4) ? WO_L4P : WO_L6P) + e] = __float2bfloat16(acc);
    return;
  }
  int O, I, OP, off;
  const float* w;
  if (job == 1)      { O = 32; I = 32; OP = 32; off = WO_L1; w = wp.w[1]; }
  else if (job == 2) { O = 64; I = 32; OP = 64; off = WO_L2; w = wp.w[2]; }
  else if (job == 3) { O = 64; I = 64; OP = 64; off = WO_L3; w = wp.w[3]; }
  else if (job == 5) { O = 32; I = 64; OP = 32; off = WO_L5; w = wp.w[5]; }
  else if (job == 7) { O = 2;  I = 32; OP = 16; off = WO_L7; w = wp.w[7]; }
  else if (job == 8) { O = 64; I = 64; OP = 64; off = WO_L4U; w = wp.w[4]; }
  else               { O = 32; I = 32; OP = 32; off = WO_L6U; w = wp.w[6]; }
  const int NCH = I >> 5;
  const int n = NCH * 9 * OP * 32;
  if (e >= n) return;
  int ic = e & 31;
  int o = (e >> 5) % OP;
  int tap = (e / (32 * OP)) % 9;
  int ch = e / (9 * 32 * OP);
  int i = ch * 32 + ic;
  float v = 0.0f;
  if (o < O) v = w[(o * I + i) * 9 + tap];
  dst[off + e] = __float2bfloat16(v);
}

// ---------------------------------------------------------------------------
// pack_x: NCHW f32 (3ch) -> NHWC-8 bf16 (ch 3..7 zero)
// ---------------------------------------------------------------------------
__global__ __launch_bounds__(256) void pack_x(const float* __restrict__ x,
                                              bf16* __restrict__ xp) {
  int i = blockIdx.x * 256 + threadIdx.x;
  if (i >= BATCH * HH * WW) return;
  int b = i / (HH * WW);
  int px = i - b * (HH * WW);
  union { uint4 v; ushort_t s[8]; } o;
  o.v = make_uint4(0, 0, 0, 0);
  const float* p = x + (long)b * 3 * HH * WW + px;
  o.s[0] = f2bfu(p[0]);
  o.s[1] = f2bfu(p[HH * WW]);
  o.s[2] = f2bfu(p[2 * HH * WW]);
  *(uint4*)&xp[(long)i * 8] = o.v;
}

// ---------------------------------------------------------------------------
// conv01_k: FUSED conv0 (tap-packed, relu) + conv1 (3x3, relu, 2x2 maxpool).
// conv0 output never leaves LDS.
// ---------------------------------------------------------------------------
__global__ __launch_bounds__(512) void conv01_k(
    const bf16* __restrict__ xp, const bf16* __restrict__ w0,
    const bf16* __restrict__ w1, const float* __restrict__ b0,
    const float* __restrict__ b1, bf16* __restrict__ out) {
  __shared__ alignas(16) bf16 xp_lds[720 * 8];    // 36x20 double-halo, 8ch
  __shared__ alignas(16) bf16 mid_lds[612 * 32];  // 34x18 conv0 out
  __shared__ alignas(16) bf16 w0_lds[3072];
  __shared__ alignas(16) bf16 w1_lds[9 * 32 * 32];
  const int tid = threadIdx.x;
  const int lane = tid & 63;
  const int wid = tid >> 6;
  const int lm = lane & 15;
  const int quad = lane >> 4;
  const int x0 = blockIdx.x * 16, y0 = blockIdx.y * 32;
  const int b = blockIdx.z;

  for (int u = tid; u < 720; u += 512) {
    int hy = u / 20, hx = u - hy * 20;
    int gy = y0 - 2 + hy, gx = x0 - 2 + hx;
    uint4 v = make_uint4(0, 0, 0, 0);
    if (gy >= 0 && gy < HH && gx >= 0 && gx < WW)
      v = *(const uint4*)(xp + (((long)b * HH + gy) * WW + gx) * 8);
    *(uint4*)&xp_lds[u * 8] = v;
  }
  if (tid < 384) *(uint4*)&w0_lds[tid * 8] = *(const uint4*)(w0 + tid * 8);
  for (int j = wid; j < 18; j += 8)
    dma16((char*)w1_lds + j * 1024, (const char*)w1 + j * 1024 + lane * 16);
  __syncthreads();

  // ---- conv0 -> mid_lds (612 px; relu; zero where halo px is image-OOB) ----
  for (int t = wid; t < 39; t += 8) {
    int px = t * 16 + lm;              // 0..623; valid < 612
    int pxc = min(px, 611);
    int hy = pxc / 18, hx = pxc - hy * 18;
    float4v acc0[2];
#pragma unroll
    for (int mt = 0; mt < 2; ++mt)
      acc0[mt] = *(const float4v*)(b0 + mt * 16 + quad * 4);
#pragma unroll
    for (int g = 0; g < 3; ++g) {
      int tap = g * 4 + quad;
      if (tap > 8) tap = 8;  // clamped taps have zero A-weights
      int r = (tap * 11) >> 5;
      int s = tap - r * 3;
      short8 bfr = *(const short8*)&xp_lds[((hy + r) * 20 + hx + s) * 8];
      short8 a0 = *(const short8*)&w0_lds[quad * 768 + (g * 32 + lm) * 8];
      short8 a1 = *(const short8*)&w0_lds[quad * 768 + (g * 32 + 16 + lm) * 8];
      acc0[0] = __builtin_amdgcn_mfma_f32_16x16x32_bf16(a0, bfr, acc0[0], 0, 0, 0);
      acc0[1] = __builtin_amdgcn_mfma_f32_16x16x32_bf16(a1, bfr, acc0[1], 0, 0, 0);
    }
    int gy = y0 - 1 + hy, gx = x0 - 1 + hx;
    bool inimg = (gy >= 0) && (gy < HH) && (gx >= 0) && (gx < WW);
    if (px < 612) {
#pragma unroll
      for (int mt = 0; mt < 2; ++mt) {
        union { uint2 v; ushort_t s2[4]; } pk;
#pragma unroll
        for (int r2 = 0; r2 < 4; ++r2)
          pk.s2[r2] = inimg ? f2bfu(fmaxf(acc0[mt][r2], 0.0f)) : (ushort_t)0;
        *(uint2*)&mid_lds[px * 32 + mt * 16 + quad * 4] = pk.v;
      }
    }
  }
  __syncthreads();

  // ---- conv1 from mid_lds + relu + 2x2 maxpool -> out [256,256,32] ----
  float4v acc[2][4];
#pragma unroll
  for (int mt = 0; mt < 2; ++mt) {
    float4v bv = *(const float4v*)(b1 + mt * 16 + quad * 4);
#pragma unroll
    for (int nt = 0; nt < 4; ++nt) acc[mt][nt] = bv;
  }
#pragma unroll
  for (int tap = 0; tap < 9; ++tap) {
    const int r = tap / 3, s = tap - r * 3;
    short8 afrag[2], bfrag[4];
#pragma unroll
    for (int mt = 0; mt < 2; ++mt)
      afrag[mt] = *(const short8*)&w1_lds[(tap * 32 + mt * 16 + lm) * 32 + quad * 8];
#pragma unroll
    for (int nt = 0; nt < 4; ++nt) {
      int py = 4 * wid + nt;
      bfrag[nt] = *(const short8*)&mid_lds[((py + r) * 18 + lm + s) * 32 + quad * 8];
    }
#pragma unroll
    for (int mt = 0; mt < 2; ++mt)
#pragma unroll
      for (int nt = 0; nt < 4; ++nt)
        acc[mt][nt] = __builtin_amdgcn_mfma_f32_16x16x32_bf16(
            afrag[mt], bfrag[nt], acc[mt][nt], 0, 0, 0);
  }
  const int Ho = HH >> 1, Wo = WW >> 1;
#pragma unroll
  for (int mt = 0; mt < 2; ++mt) {
#pragma unroll
    for (int g = 0; g < 2; ++g) {
      float4v m;
#pragma unroll
      for (int r = 0; r < 4; ++r)
        m[r] = fmaxf(fmaxf(acc[mt][2 * g][r], acc[mt][2 * g + 1][r]), 0.0f);
#pragma unroll
      for (int r = 0; r < 4; ++r) m[r] = fmaxf(m[r], __shfl_xor(m[r], 1, 64));
      if ((lm & 1) == 0) {
        int pyo = (y0 >> 1) + 2 * wid + g;
        int pxo = (x0 >> 1) + (lm >> 1);
        union { uint2 v; ushort_t s[4]; } pk;
#pragma unroll
        for (int r = 0; r < 4; ++r) pk.s[r] = f2bfu(m[r]);
        *(uint2*)&out[(((long)b * Ho + pyo) * Wo + pxo) * 32 + mt * 16 +
                      quad * 4] = pk.v;
      }
    }
  }
}

// ---------------------------------------------------------------------------
// Implicit-GEMM 3x3 conv (pad 1), NHWC bf16. 8 waves, 32(t) x 16(w) tile.
// OUT_MODE: 0 = NHWC bf16 (+relu); 2 = flow NCHW f32 (tanh) + fused deformed;
//           3 = NHWC bf16, fused relu + 2x2 maxpool.
// ---------------------------------------------------------------------------
template <int CIN, int COUT, int COUTR, int OUT_MODE>
__global__ __launch_bounds__(512) void conv_mfma(
    const bf16* __restrict__ in, const bf16* __restrict__ wt,
    const float* __restrict__ bias, void* __restrict__ out_, int H, int W,
    const float* __restrict__ temp, float* __restrict__ def) {
  constexpr int MT = COUT / 16;
  constexpr int CK = 32;
  __shared__ alignas(16) bf16 in_lds[612 * CK];  // 34x18 halo x 32ch
  __shared__ alignas(16) bf16 w_lds[9 * COUT * CK];
  const int tid = threadIdx.x;
  const int lane = tid & 63;
  const int wid = tid >> 6;  // 0..7
  const int lm = lane & 15;
  const int quad = lane >> 4;
  const int x0 = blockIdx.x * 16;
  const int y0 = blockIdx.y * 32;
  const int b = blockIdx.z;

  float4v acc[MT][4];
#pragma unroll
  for (int mt = 0; mt < MT; ++mt) {
    float4v bv;
    if constexpr (COUTR == COUT) {
      bv = *(const float4v*)(bias + mt * 16 + quad * 4);
    } else {
#pragma unroll
      for (int r = 0; r < 4; ++r) {
        int co = mt * 16 + quad * 4 + r;
        bv[r] = (co < COUTR) ? bias[co] : 0.0f;
      }
    }
#pragma unroll
    for (int nt = 0; nt < 4; ++nt) acc[mt][nt] = bv;
  }

  const bool interior =
      (x0 >= 1) && (x0 + 16 <= W - 1) && (y0 >= 1) && (y0 + 32 <= H - 1);
  for (int c0 = 0; c0 < CIN; c0 += CK) {
    if (interior) {
      for (int r = wid; r < 34; r += 8) {
        int gy = y0 - 1 + r;
        const bf16* gsrc = in + (((long)b * H + gy) * W + x0) * CIN + c0 +
                           (lane >> 2) * CIN + (lane & 3) * 8;
        dma16(&in_lds[(r * 18 + 1) * CK], gsrc);
      }
      if (tid < 272) {
        int r = tid >> 3;
        int side = (tid >> 2) & 1;
        int seg = tid & 3;
        int gx = side ? (x0 + 16) : (x0 - 1);
        int gy = y0 - 1 + r;
        uint4 v = *(const uint4*)(in + (((long)b * H + gy) * W + gx) * CIN +
                                  c0 + seg * 8);
        *(uint4*)&in_lds[(r * 18 + (side ? 17 : 0)) * CK + seg * 8] = v;
      }
    } else {
      for (int u = tid; u < 612 * 4; u += 512) {
        int px = u >> 2;
        int seg = u & 3;
        int hy = px / 18, hx = px - hy * 18;
        int gy = y0 - 1 + hy, gx = x0 - 1 + hx;
        uint4 v = make_uint4(0, 0, 0, 0);
        if (gy >= 0 && gy < H && gx >= 0 && gx < W)
          v = *(const uint4*)(in + (((long)b * H + gy) * W + gx) * CIN + c0 +
                              seg * 8);
        *(uint4*)&in_lds[px * CK + seg * 8] = v;
      }
    }
    {
      const char* wsrc = (const char*)(wt + (size_t)(c0 >> 5) * 9 * COUT * CK);
      constexpr int WCH = 9 * COUT * CK * 2 / 1024;
      for (int j = wid; j < WCH; j += 8)
        dma16((char*)w_lds + j * 1024, wsrc + j * 1024 + lane * 16);
    }
    __syncthreads();

#pragma unroll
    for (int tap = 0; tap < 9; ++tap) {
      const int r = tap / 3, s = tap - r * 3;
      short8 afrag[MT], bfrag[4];
#pragma unroll
      for (int mt = 0; mt < MT; ++mt)
        afrag[mt] =
            *(const short8*)&w_lds[(tap * COUT + mt * 16 + lm) * CK + quad * 8];
#pragma unroll
      for (int nt = 0; nt < 4; ++nt) {
        int py = 4 * wid + nt;
        bfrag[nt] =
            *(const short8*)&in_lds[((py + r) * 18 + lm + s) * CK + quad * 8];
      }
#pragma unroll
      for (int mt = 0; mt < MT; ++mt)
#pragma unroll
        for (int nt = 0; nt < 4; ++nt)
          acc[mt][nt] = __builtin_amdgcn_mfma_f32_16x16x32_bf16(
              afrag[mt], bfrag[nt], acc[mt][nt], 0, 0, 0);
    }
    __syncthreads();
  }

  if constexpr (OUT_MODE == 3) {
    bf16* out = (bf16*)out_;
    const int Ho = H >> 1, Wo = W >> 1;
#pragma unroll
    for (int mt = 0; mt < MT; ++mt) {
#pragma unroll
      for (int g = 0; g < 2; ++g) {
        float4v m;
#pragma unroll
        for (int r = 0; r < 4; ++r)
          m[r] = fmaxf(fmaxf(acc[mt][2 * g][r], acc[mt][2 * g + 1][r]), 0.0f);
#pragma unroll
        for (int r = 0; r < 4; ++r) m[r] = fmaxf(m[r], __shfl_xor(m[r], 1, 64));
        if ((lm & 1) == 0) {
          int pyo = (y0 >> 1) + 2 * wid + g;
          int pxo = (x0 >> 1) + (lm >> 1);
          union { uint2 v; ushort_t s[4]; } pk;
#pragma unroll
          for (int r = 0; r < 4; ++r) pk.s[r] = f2bfu(m[r]);
          *(uint2*)&out[(((long)b * Ho + pyo) * Wo + pxo) * COUT + mt * 16 +
                        quad * 4] = pk.v;
        }
      }
    }
  } else {
#pragma unroll
    for (int mt = 0; mt < MT; ++mt) {
#pragma unroll
      for (int nt = 0; nt < 4; ++nt) {
        int gy = y0 + 4 * wid + nt;
        int gx = x0 + lm;
        float4v v = acc[mt][nt];
        if constexpr (OUT_MODE == 0) {
          bf16* out = (bf16*)out_;
          union { uint2 v; ushort_t s[4]; } pk;
#pragma unroll
          for (int r = 0; r < 4; ++r) pk.s[r] = f2bfu(fmaxf(v[r], 0.0f));
          *(uint2*)&out[(((long)b * H + gy) * W + gx) * COUT + mt * 16 +
                        quad * 4] = pk.v;
        } else {
          float* out = (float*)out_;
          if (quad == 0) {
            float fx = tanhf(v[0]);
            float fy = tanhf(v[1]);
            out[(((long)b * 2 + 0) * H + gy) * (long)W + gx] = fx;
            out[(((long)b * 2 + 1) * H + gy) * (long)W + gx] = fy;
            float T = temp[0];
            float2 d;
            d.x = -1.0f + gx * (2.0f / 511.0f) + fx * T;
            d.y = -1.0f + gy * (2.0f / 511.0f) + fy * T;
            *(float2*)&def[(((long)b * HH + gy) * WW + gx) * 2] = d;
          }
        }
      }
    }
  }
}

// ---------------------------------------------------------------------------
// conv_up: fused (x2 bilinear upsample -> 3x3 conv -> relu).
// Bulk blocks: phase-conv on HALF-res grid with folded weights; stores skip
//   the 16-px output border band.
// Edge blocks: exact fused upsample-conv for perimeter 16x16 output tiles;
//   MT split across wave halves so all 8 waves do MFMA.
// PSPLIT=true  (conv4, CIN=64): blockIdx.z = b*4+ph, single phase per block.
// PSPLIT=false (conv6, CIN=32==CK): input staged once; phases fused in
//   dy-PAIRS sharing B-fragment reads (per tap: 4 bfrag + 4 afrag -> 16 MFMA).
// ---------------------------------------------------------------------------
template <int CIN, int COUT, bool PSPLIT>
__global__ __launch_bounds__(512) void conv_up(
    const bf16* __restrict__ in, const bf16* __restrict__ wtP,
    const bf16* __restrict__ wtU, const float* __restrict__ bias,
    bf16* __restrict__ out, int Ho, int Wo) {
  constexpr int MT = COUT / 16;
  constexpr int MH = MT / 2;  // mts per wave-half (edge path)
  constexpr int CK = 32;
  constexpr int WSZ = 9 * COUT * CK;
  constexpr int WBUF = PSPLIT ? WSZ : 2 * WSZ;  // 36864 B either way
  __shared__ alignas(16) bf16 in_lds[612 * CK];
  __shared__ alignas(16) bf16 w_lds[WBUF];
  const int tid = threadIdx.x;
  const int lane = tid & 63;
  const int wid = tid >> 6;
  const int lm = lane & 15;
  const int quad = lane >> 4;
  const int Hs = Ho >> 1, Ws = Wo >> 1;
  const int nx = Ws >> 4, ny = Hs >> 5;
  const int bulkN = nx * ny;
  const int b = PSPLIT ? (blockIdx.z >> 2) : blockIdx.z;
  const int ph0 = PSPLIT ? (blockIdx.z & 3) : 0;
  const int t = blockIdx.x;

  if (t >= bulkN) {
    // ================= edge path (exact, owns 16-px border band) ==========
    if (PSPLIT && ph0 != 0) return;
    const int G = Wo >> 4;
    int e = t - bulkN;
    int tx, ty;
    if (e < G) { ty = 0; tx = e; }
    else if (e < 2 * G) { ty = G - 1; tx = e - G; }
    else { int u = e - 2 * G; ty = 1 + (u >> 1); tx = (u & 1) ? (G - 1) : 0; }
    const int x0 = tx * 16, y0 = ty * 16;
    const int wrow = wid & 3;          // row group 0..3
    const int wmt = (wid >> 2) * MH;   // first mt of this wave-half

    float4v acc[MH][4];
#pragma unroll
    for (int m = 0; m < MH; ++m) {
      float4v bv = *(const float4v*)(bias + (wmt + m) * 16 + quad * 4);
#pragma unroll
      for (int nt = 0; nt < 4; ++nt) acc[m][nt] = bv;
    }

    for (int c0 = 0; c0 < CIN; c0 += CK) {
      for (int u = tid; u < 324 * 4; u += 512) {
        int px = u >> 2;
        int seg = u & 3;
        int hy = px / 18, hx = px - hy * 18;
        int gy = y0 - 1 + hy, gx = x0 - 1 + hx;
        uint4 o = make_uint4(0, 0, 0, 0);
        if (gy >= 0 && gy < Ho && gx >= 0 && gx < Wo) {
          int ys = (gy >> 1) - ((gy & 1) ? 0 : 1);
          int xs = (gx >> 1) - ((gx & 1) ? 0 : 1);
          float wy = (gy & 1) ? 0.25f : 0.75f;
          float wx = (gx & 1) ? 0.25f : 0.75f;
          int y0c = max(ys, 0), y1c = min(ys + 1, Hs - 1);
          int x0c = max(xs, 0), x1c = min(xs + 1, Ws - 1);
          const bf16* p = in + ((long)b * Hs * Ws) * CIN + c0 + seg * 8;
          union { uint4 v; ushort_t s[8]; } a00, a01, a10, a11, r;
          a00.v = *(const uint4*)(p + ((long)y0c * Ws + x0c) * CIN);
          a01.v = *(const uint4*)(p + ((long)y0c * Ws + x1c) * CIN);
          a10.v = *(const uint4*)(p + ((long)y1c * Ws + x0c) * CIN);
          a11.v = *(const uint4*)(p + ((long)y1c * Ws + x1c) * CIN);
#pragma unroll
          for (int j = 0; j < 8; ++j) {
            float f = (1.0f - wy) * ((1.0f - wx) * bfu2f(a00.s[j]) +
                                     wx * bfu2f(a01.s[j])) +
                      wy * ((1.0f - wx) * bfu2f(a10.s[j]) +
                            wx * bfu2f(a11.s[j]));
            r.s[j] = f2bfu(f);
          }
          o = r.v;
        }
        *(uint4*)&in_lds[px * CK + seg * 8] = o;
      }
      {
        const char* wsrc = (const char*)(wtU + (size_t)(c0 >> 5) * WSZ);
        constexpr int WCH = WSZ * 2 / 1024;
        for (int j = wid; j < WCH; j += 8)
          dma16((char*)w_lds + j * 1024, wsrc + j * 1024 + lane * 16);
      }
      __syncthreads();
#pragma unroll
      for (int tap = 0; tap < 9; ++tap) {
        const int r = tap / 3, s = tap - r * 3;
        short8 afrag[MH], bfrag[4];
#pragma unroll
        for (int m = 0; m < MH; ++m)
          afrag[m] = *(const short8*)&w_lds[(tap * COUT + (wmt + m) * 16 + lm) * CK +
                                            quad * 8];
#pragma unroll
        for (int nt = 0; nt < 4; ++nt) {
          int py = 4 * wrow + nt;
          bfrag[nt] =
              *(const short8*)&in_lds[((py + r) * 18 + lm + s) * CK + quad * 8];
        }
#pragma unroll
        for (int m = 0; m < MH; ++m)
#pragma unroll
          for (int nt = 0; nt < 4; ++nt)
            acc[m][nt] = __builtin_amdgcn_mfma_f32_16x16x32_bf16(
                afrag[m], bfrag[nt], acc[m][nt], 0, 0, 0);
      }
      __syncthreads();
    }
#pragma unroll
    for (int m = 0; m < MH; ++m)
#pragma unroll
      for (int nt = 0; nt < 4; ++nt) {
        int gy = y0 + 4 * wrow + nt;
        int gx = x0 + lm;
        union { uint2 v; ushort_t s[4]; } pk;
#pragma unroll
        for (int r = 0; r < 4; ++r) pk.s[r] = f2bfu(fmaxf(acc[m][nt][r], 0.0f));
        *(uint2*)&out[(((long)b * Ho + gy) * Wo + gx) * COUT + (wmt + m) * 16 +
                      quad * 4] = pk.v;
      }
    return;
  }

  // ================== bulk path (phase conv, folded weights) ==============
  const int bx = t % nx, by = t / nx;
  const int xs0 = bx * 16, ys0 = by * 32;
  const bool interior = (bx >= 1) && (bx < nx - 1) && (by >= 1) && (by < ny - 1);

  if constexpr (!PSPLIT) {
    // CIN == CK: input staged once; dy-pairs of phases fused (shared bfrag).
    static_assert(CIN == CK, "non-split bulk path assumes single K chunk");
    if (interior) {
      for (int r = wid; r < 34; r += 8) {
        int gy = ys0 - 1 + r;
        const bf16* gsrc = in + (((long)b * Hs + gy) * Ws + xs0) * CIN +
                           (lane >> 2) * CIN + (lane & 3) * 8;
        dma16(&in_lds[(r * 18 + 1) * CK], gsrc);
      }
      if (tid < 272) {
        int r = tid >> 3;
        int side = (tid >> 2) & 1;
        int seg = tid & 3;
        int gx = side ? (xs0 + 16) : (xs0 - 1);
        int gy = ys0 - 1 + r;
        uint4 v = *(const uint4*)(in + (((long)b * Hs + gy) * Ws + gx) * CIN +
                                  seg * 8);
        *(uint4*)&in_lds[(r * 18 + (side ? 17 : 0)) * CK + seg * 8] = v;
      }
    } else {
      for (int u = tid; u < 612 * 4; u += 512) {
        int px = u >> 2;
        int seg = u & 3;
        int hy = px / 18, hx = px - hy * 18;
        int sy = min(max(ys0 - 1 + hy, 0), Hs - 1);
        int sx = min(max(xs0 - 1 + hx, 0), Ws - 1);
        uint4 v = *(const uint4*)(in + (((long)b * Hs + sy) * Ws + sx) * CIN +
                                  seg * 8);
        *(uint4*)&in_lds[px * CK + seg * 8] = v;
      }
    }
    constexpr int WCH = 2 * WSZ * 2 / 1024;  // both phases of a pair
    for (int pair = 0; pair < 2; ++pair) {
      {
        const char* wsrc = (const char*)(wtP + (size_t)(2 * pair) * WSZ);
        for (int j = wid; j < WCH; j += 8)
          dma16((char*)w_lds + j * 1024, wsrc + j * 1024 + lane * 16);
      }
      __syncthreads();
      float4v acc[2][MT][4];
#pragma unroll
      for (int p = 0; p < 2; ++p)
#pragma unroll
        for (int mt = 0; mt < MT; ++mt) {
          float4v bv = *(const float4v*)(bias + mt * 16 + quad * 4);
#pragma unroll
          for (int nt = 0; nt < 4; ++nt) acc[p][mt][nt] = bv;
        }
#pragma unroll
      for (int tap = 0; tap < 9; ++tap) {
        const int r = tap / 3, s = tap - r * 3;
        short8 bfrag[4], afrag[2][MT];
#pragma unroll
        for (int nt = 0; nt < 4; ++nt) {
          int py = 4 * wid + nt;
          bfrag[nt] =
              *(const short8*)&in_lds[((py + r) * 18 + lm + s) * CK + quad * 8];
        }
#pragma unroll
        for (int p = 0; p < 2; ++p)
#pragma unroll
          for (int mt = 0; mt < MT; ++mt)
            afrag[p][mt] = *(const short8*)&w_lds[p * WSZ +
                (tap * COUT + mt * 16 + lm) * CK + quad * 8];
#pragma unroll
        for (int p = 0; p < 2; ++p)
#pragma unroll
          for (int mt = 0; mt < MT; ++mt)
#pragma unroll
            for (int nt = 0; nt < 4; ++nt)
              acc[p][mt][nt] = __builtin_amdgcn_mfma_f32_16x16x32_bf16(
                  afrag[p][mt], bfrag[nt], acc[p][mt][nt], 0, 0, 0);
      }
      const int dy = pair;
#pragma unroll
      for (int p = 0; p < 2; ++p) {
        const int dx = p;
#pragma unroll
        for (int mt = 0; mt < MT; ++mt)
#pragma unroll
          for (int nt = 0; nt < 4; ++nt) {
            int gy = 2 * (ys0 + 4 * wid + nt) + dy;
            int gx = 2 * (xs0 + lm) + dx;
            if (gy >= 16 && gy < Ho - 16 && gx >= 16 && gx < Wo - 16) {
              union { uint2 v; ushort_t s2[4]; } pk;
#pragma unroll
              for (int r2 = 0; r2 < 4; ++r2)
                pk.s2[r2] = f2bfu(fmaxf(acc[p][mt][nt][r2], 0.0f));
              *(uint2*)&out[(((long)b * Ho + gy) * Wo + gx) * COUT + mt * 16 +
                            quad * 4] = pk.v;
            }
          }
      }
      __syncthreads();  // protect w_lds before next pair's staging
    }
    return;
  }

  // PSPLIT bulk: one phase per block, multi-chunk K, single-buffered.
  const int ph = ph0;
  float4v acc[MT][4];
#pragma unroll
  for (int mt = 0; mt < MT; ++mt) {
    float4v bv = *(const float4v*)(bias + mt * 16 + quad * 4);
#pragma unroll
    for (int nt = 0; nt < 4; ++nt) acc[mt][nt] = bv;
  }
  for (int c0 = 0; c0 < CIN; c0 += CK) {
    if (interior) {
      for (int r = wid; r < 34; r += 8) {
        int gy = ys0 - 1 + r;
        const bf16* gsrc = in + (((long)b * Hs + gy) * Ws + xs0) * CIN +
                           c0 + (lane >> 2) * CIN + (lane & 3) * 8;
        dma16(&in_lds[(r * 18 + 1) * CK], gsrc);
      }
      if (tid < 272) {
        int r = tid >> 3;
        int side = (tid >> 2) & 1;
        int seg = tid & 3;
        int gx = side ? (xs0 + 16) : (xs0 - 1);
        int gy = ys0 - 1 + r;
        uint4 v = *(const uint4*)(in + (((long)b * Hs + gy) * Ws + gx) * CIN +
                                  c0 + seg * 8);
        *(uint4*)&in_lds[(r * 18 + (side ? 17 : 0)) * CK + seg * 8] = v;
      }
    } else {
      for (int u = tid; u < 612 * 4; u += 512) {
        int px = u >> 2;
        int seg = u & 3;
        int hy = px / 18, hx = px - hy * 18;
        int sy = min(max(ys0 - 1 + hy, 0), Hs - 1);
        int sx = min(max(xs0 - 1 + hx, 0), Ws - 1);
        uint4 v = *(const uint4*)(in + (((long)b * Hs + sy) * Ws + sx) * CIN +
                                  seg * 8);
        *(uint4*)&in_lds[px * CK + seg * 8] = v;
      }
    }
    {
      const char* wsrc = (const char*)(wtP + (size_t)(ph * (CIN / CK) + (c0 >> 5)) * WSZ);
      constexpr int WCH = WSZ * 2 / 1024;
      for (int j = wid; j < WCH; j += 8)
        dma16((char*)w_lds + j * 1024, wsrc + j * 1024 + lane * 16);
    }
    __syncthreads();
#pragma unroll
    for (int tap = 0; tap < 9; ++tap) {
      const int r = tap / 3, s = tap - r * 3;
      short8 afrag[MT], bfrag[4];
#pragma unroll
      for (int mt = 0; mt < MT; ++mt)
        afrag[mt] =
            *(const short8*)&w_lds[(tap * COUT + mt * 16 + lm) * CK + quad * 8];
#pragma unroll
      for (int nt = 0; nt < 4; ++nt) {
        int py = 4 * wid + nt;
        bfrag[nt] =
            *(const short8*)&in_lds[((py + r) * 18 + lm + s) * CK + quad * 8];
      }
#pragma unroll
      for (int mt = 0; mt < MT; ++mt)
#pragma unroll
        for (int nt = 0; nt < 4; ++nt)
          acc[mt][nt] = __builtin_amdgcn_mfma_f32_16x16x32_bf16(
              afrag[mt], bfrag[nt], acc[mt][nt], 0, 0, 0);
    }
    __syncthreads();
  }
  const int dy = ph >> 1, dx = ph & 1;
#pragma unroll
  for (int mt = 0; mt < MT; ++mt)
#pragma unroll
    for (int nt = 0; nt < 4; ++nt) {
      int gy = 2 * (ys0 + 4 * wid + nt) + dy;
      int gx = 2 * (xs0 + lm) + dx;
      if (gy >= 16 && gy < Ho - 16 && gx >= 16 && gx < Wo - 16) {
        union { uint2 v; ushort_t s2[4]; } pk;
#pragma unroll
        for (int r2 = 0; r2 < 4; ++r2)
          pk.s2[r2] = f2bfu(fmaxf(acc[mt][nt][r2], 0.0f));
        *(uint2*)&out[(((long)b * Ho + gy) * Wo + gx) * COUT + mt * 16 +
                      quad * 4] = pk.v;
      }
    }
}

// ---------------------------------------------------------------------------
// patches: grid_sample bilinear, zeros padding -> out [B,256,3,64,64]
// ---------------------------------------------------------------------------
__global__ __launch_bounds__(256) void patches_k(const float* __restrict__ x,
                                                 const float* __restrict__ def,
                                                 float* __restrict__ out) {
  int i = blockIdx.x * 256 + threadIdx.x;
  int pj = i & 63;
  int t = i >> 6;
  int pi = t & 63;
  t >>= 6;
  int n = t & 255;
  int b = t >> 8;
  if (b >= BATCH) return;
  int hi = n >> 4, wi = n & 15;
  const float* dptr = def + (((long)b * HH + hi * 32) * WW + wi * 32) * 2;
  float cx = dptr[0], cy = dptr[1];
  float pgx = cx + (-1.0f + pj * (2.0f / 63.0f)) * 0.125f;
  float pgy = cy + (-1.0f + pi * (2.0f / 63.0f)) * 0.125f;
  float ix = ((pgx + 1.0f) * 512.0f - 1.0f) * 0.5f;
  float iy = ((pgy + 1.0f) * 512.0f - 1.0f) * 0.5f;
  float fx0 = floorf(ix), fy0 = floorf(iy);
  float wx1 = ix - fx0, wy1 = iy - fy0;
  int x0 = (int)fx0, y0 = (int)fy0;
  int x1 = x0 + 1, y1 = y0 + 1;
  bool vx0 = (x0 >= 0) && (x0 <= 511), vx1 = (x1 >= 0) && (x1 <= 511);
  bool vy0 = (y0 >= 0) && (y0 <= 511), vy1 = (y1 >= 0) && (y1 <= 511);
  int cx0 = min(max(x0, 0), 511), cx1 = min(max(x1, 0), 511);
  int cy0 = min(max(y0, 0), 511), cy1 = min(max(y1, 0), 511);
  float w00 = (1.0f - wx1) * (1.0f - wy1) * ((vx0 && vy0) ? 1.0f : 0.0f);
  float w01 = wx1 * (1.0f - wy1) * ((vx1 && vy0) ? 1.0f : 0.0f);
  float w10 = (1.0f - wx1) * wy1 * ((vx0 && vy1) ? 1.0f : 0.0f);
  float w11 = wx1 * wy1 * ((vx1 && vy1) ? 1.0f : 0.0f);
#pragma unroll
  for (int c = 0; c < 3; ++c) {
    const float* img = x + ((long)b * 3 + c) * (HH * WW);
    float v = img[cy0 * WW + cx0] * w00 + img[cy0 * WW + cx1] * w01 +
              img[cy1 * WW + cx0] * w10 + img[cy1 * WW + cx1] * w11;
    out[(((long)b * 256 + n) * 3 + c) * 4096 + pi * 64 + pj] = v;
  }
}

// ---------------------------------------------------------------------------

extern "C" void kernel_launch(void* const* d_in, const int* in_sizes, int n_in,
                              void* d_out, int out_size, void* d_ws,
                              size_t ws_size, hipStream_t stream) {
  const float* x = (const float*)d_in[0];
  WP wp;
  const float* bs[8];
  for (int i = 0; i < 8; ++i) {
    wp.w[i] = (const float*)d_in[1 + 2 * i];
    bs[i] = (const float*)d_in[2 + 2 * i];
  }
  const float* temp = (const float*)d_in[17];

  float* out = (float*)d_out;
  float* flow = out + 12582912;  // [B,2,512,512] f32
  float* def = out + 14680064;   // [B,512,512,2] f32
  bf16* wT = (bf16*)d_out;       // weight stash; patches_k overwrites LAST

  const size_t bufElems = (size_t)BATCH * 512 * 512 * 32;
  bf16* A = (bf16*)d_ws;
  bf16* Bf = A + bufElems;
  bf16* xp = Bf + bufElems;

  prep_w<<<dim3(576, 10), 256, 0, stream>>>(wp, wT);
  pack_x<<<(BATCH * HH * WW) / 256, 256, 0, stream>>>(x, xp);

  // fused conv0+conv1 (+relu+pool): xp -> Bf [256,256,32]
  conv01_k<<<dim3(32, 16, BATCH), 512, 0, stream>>>(
      xp, wT + WO_L0, wT + WO_L1, bs[0], bs[1], Bf);
  // conv2: Bf -> A [256,256,64]
  conv_mfma<32, 64, 64, 0><<<dim3(16, 8, BATCH), 512, 0, stream>>>(
      Bf, wT + WO_L2, bs[2], A, 256, 256, nullptr, nullptr);
  // conv3 + relu + pool: A -> Bf [128,128,64]
  conv_mfma<64, 64, 64, 3><<<dim3(16, 8, BATCH), 512, 0, stream>>>(
      A, wT + WO_L3, bs[3], Bf, 256, 256, nullptr, nullptr);
  // conv4 (phase-split up1 + fused edge): Bf(128² src) -> A [256,256,64]
  conv_up<64, 64, true><<<dim3(8 * 4 + 60, 1, 4 * BATCH), 512, 0, stream>>>(
      Bf, wT + WO_L4P, wT + WO_L4U, bs[4], A, 256, 256);
  // conv5: A -> Bf [256,256,32]
  conv_mfma<64, 32, 32, 0><<<dim3(16, 8, BATCH), 512, 0, stream>>>(
      A, wT + WO_L5, bs[5], Bf, 256, 256, nullptr, nullptr);
  // conv6 (dy-pair-fused phases + fused edge): Bf(256² src) -> A [512,512,32]
  conv_up<32, 32, false><<<dim3(16 * 8 + 124, 1, BATCH), 512, 0, stream>>>(
      Bf, wT + WO_L6P, wT + WO_L6U, bs[6], A, 512, 512);
  // conv7 + tanh + fused deformed: A -> flow + def
  conv_mfma<32, 16, 2, 2><<<dim3(32, 16, BATCH), 512, 0, stream>>>(
      A, wT + WO_L7, bs[7], flow, 512, 512, temp, def);
  // patches (overwrites the wT stash)
  patches_k<<<(BATCH * 256 * 64 * 64) / 256, 256, 0, stream>>>(x, def, out);
}